// Round 1
// baseline (826.809 us; speedup 1.0000x reference)
//
#include <hip/hip_runtime.h>

// SGA_75531294867605 — GRU x2 -> cos-sim topK concept graph -> softmax attention head.
// Round 1: correct fused implementation. bf16 MFMA for all big GEMMs/recurrence,
// fp32 everywhere else. Workspace ~108MB with buffer overlays.

typedef float f32x4 __attribute__((ext_vector_type(4)));
typedef short s16x8 __attribute__((ext_vector_type(8)));
typedef unsigned short u16;

#define DEVFN static __device__ __forceinline__

DEVFN u16 f2bf(float f) {
  union { float f; unsigned u; } v; v.f = f;
  return (u16)((v.u + 0x7FFFu + ((v.u >> 16) & 1u)) >> 16);  // RNE
}

DEVFN f32x4 mfma16(s16x8 a, s16x8 b, f32x4 c) {
  return __builtin_amdgcn_mfma_f32_16x16x32_bf16(a, b, c, 0, 0, 0);
}

DEVFN float sigmf(float x) { return __builtin_amdgcn_rcpf(1.f + __expf(-x)); }
DEVFN float tanhf_fast(float x) {
  float e = __expf(2.f * x);
  return 1.f - 2.f * __builtin_amdgcn_rcpf(e + 1.f);  // exact at +-inf limits
}
DEVFN float lrelu(float v) { return v > 0.f ? v : 0.2f * v; }

// ---------------------------------------------------------------- cvt fp32->bf16
__global__ void cvt_bf16(const float* __restrict__ src, u16* __restrict__ dst, int n) {
  int i = blockIdx.x * 256 + threadIdx.x;
  if (i < n) dst[i] = f2bf(src[i]);
}

// ---------------------------------------------------------------- fused GRU layer
// Block: 512 thr (8 waves) x 16 rows, loops all 64 timesteps. Wave w owns H-cols
// [16w,16w+16) i.e. gate columns {j, j+128, j+256}: all three gates for its cols
// stay in-register -> no cross-wave gate staging. Recurrent weights live in VGPRs
// as MFMA B-frags for the whole kernel (loop-invariant across t).
template<int LAYER>
__launch_bounds__(512, 1)
__global__ void gru_kernel(const void* __restrict__ xin,
                           const u16* __restrict__ Wih, const u16* __restrict__ Whh,
                           const float* __restrict__ bih, const float* __restrict__ bhh,
                           u16* __restrict__ hseq_out, float* __restrict__ g_out)
{
  constexpr int KIN = (LAYER == 0) ? 32 : 128;
  constexpr int NKK = KIN / 32;
  constexpr int XS  = (LAYER == 0) ? 40 : 136;   // padded LDS row strides (16B-aligned)
  const int tid  = threadIdx.x;
  const int w    = tid >> 6;
  const int l    = tid & 63;
  const int quad = l >> 4;
  const int l16  = l & 15;
  const int r0   = blockIdx.x * 16;
  const int c    = w * 16 + l16;          // this lane's H column

  __shared__ u16 sh_x[16 * XS];
  __shared__ u16 sh_hb[16 * 136];

  s16x8 Bih[3][NKK];
  s16x8 Bhh[3][4];
  float bi[3], bh[3];
#pragma unroll
  for (int g = 0; g < 3; ++g) {
    int j = g * 128 + c;
    bi[g] = bih[j];
    bh[g] = bhh[j];
#pragma unroll
    for (int kk = 0; kk < NKK; ++kk)
      Bih[g][kk] = *(const s16x8*)(Wih + j * KIN + kk * 32 + quad * 8);
#pragma unroll
    for (int kk = 0; kk < 4; ++kk)
      Bhh[g][kk] = *(const s16x8*)(Whh + j * 128 + kk * 32 + quad * 8);
  }
  float hreg[4] = {0.f, 0.f, 0.f, 0.f};     // h state, fp32, this lane's (m,c) elems
  for (int idx = tid; idx < 16 * 136; idx += 512) sh_hb[idx] = 0;

  for (int t = 0; t < 64; ++t) {
    if constexpr (LAYER == 0) {
      int r = tid >> 5, cc = tid & 31;
      float xv = ((const float*)xin)[(size_t)(r0 + r) * (64 * 32) + t * 32 + cc];
      sh_x[r * XS + cc] = f2bf(xv);
    } else {
      int r = tid >> 5, c4 = (tid & 31) * 4;
      *(ushort4*)(sh_x + r * XS + c4) =
        *(const ushort4*)((const u16*)xin + (size_t)(r0 + r) * (64 * 128) + t * 128 + c4);
    }
    __syncthreads();   // B1: x staged, prev-step h writes visible
    s16x8 ax[NKK], ah[4];
#pragma unroll
    for (int kk = 0; kk < NKK; ++kk)
      ax[kk] = *(const s16x8*)(sh_x + l16 * XS + kk * 32 + quad * 8);
#pragma unroll
    for (int kk = 0; kk < 4; ++kk)
      ah[kk] = *(const s16x8*)(sh_hb + l16 * 136 + kk * 32 + quad * 8);
    __syncthreads();   // B2: all frag reads done -> safe to overwrite sh_hb below

    f32x4 ai[3], ahh[3];
    const f32x4 zz4 = {0.f, 0.f, 0.f, 0.f};
#pragma unroll
    for (int g = 0; g < 3; ++g) { ai[g] = zz4; ahh[g] = zz4; }
#pragma unroll
    for (int g = 0; g < 3; ++g)
#pragma unroll
      for (int kk = 0; kk < NKK; ++kk) ai[g] = mfma16(ax[kk], Bih[g][kk], ai[g]);
#pragma unroll
    for (int g = 0; g < 3; ++g)
#pragma unroll
      for (int kk = 0; kk < 4; ++kk)  ahh[g] = mfma16(ah[kk], Bhh[g][kk], ahh[g]);

#pragma unroll
    for (int i = 0; i < 4; ++i) {
      int m = quad * 4 + i;                     // C-layout: row=(quad*4+i), col=l16
      float rr = sigmf(ai[0][i] + bi[0] + ahh[0][i] + bh[0]);
      float zg = sigmf(ai[1][i] + bi[1] + ahh[1][i] + bh[1]);
      float nn = tanhf_fast(ai[2][i] + bi[2] + rr * (ahh[2][i] + bh[2]));
      float hnew = (1.f - zg) * nn + zg * hreg[i];
      hreg[i] = hnew;
      u16 hb = f2bf(hnew);
      sh_hb[m * 136 + c] = hb;
      if constexpr (LAYER == 0) {
        hseq_out[(size_t)(r0 + m) * (64 * 128) + t * 128 + c] = hb;
      } else {
        if (t == 63) g_out[(size_t)(r0 + m) * 128 + c] = hnew;
      }
    }
    // next iteration's B1 protects these writes against next frag reads
  }
}

// ---------------------------------------------------------------- row norms + bf16 (+T)
template<bool TR>
__global__ void norm_cvt(const float* __restrict__ src, u16* __restrict__ dst,
                         u16* __restrict__ dstT, float* __restrict__ rn)
{
  const int tid = threadIdx.x;
  const int wv = tid >> 6, l = tid & 63;
  const int row = blockIdx.x * 4 + wv;
  float2 f2 = *(const float2*)(src + (size_t)row * 128 + l * 2);
  float s = f2.x * f2.x + f2.y * f2.y;
#pragma unroll
  for (int off = 32; off >= 1; off >>= 1) s += __shfl_xor(s, off);
  u16 b0 = f2bf(f2.x), b1 = f2bf(f2.y);
  ushort2 p; p.x = b0; p.y = b1;
  *(ushort2*)(dst + (size_t)row * 128 + l * 2) = p;
  if constexpr (TR) {
    dstT[(size_t)(l * 2) * 4096 + row]     = b0;
    dstT[(size_t)(l * 2 + 1) * 4096 + row] = b1;
  }
  if (l == 0) rn[row] = (s == 0.f) ? 0.f : rsqrtf(s);  // safe inverse norm
}

// ---------------------------------------------------------------- cos-sim GEMM
// C[i][j] = (A_i . B_j) * rnA[i] * rnB[j], A/B row-major [4096][128] bf16.
__launch_bounds__(256, 1)
__global__ void cos_gemm(const u16* __restrict__ A, const u16* __restrict__ B,
                         const float* __restrict__ rnA, const float* __restrict__ rnB,
                         float* __restrict__ C)
{
  __shared__ u16 shA[128 * 136];
  __shared__ u16 shB[128 * 136];
  const int tid = threadIdx.x;
  const int l = tid & 63, wv = tid >> 6;
  const int quad = l >> 4, l16 = l & 15;
  const int i0 = blockIdx.y * 128, j0 = blockIdx.x * 128;
  {
    int r = tid >> 1, half = tid & 1;
    const int4* sa = (const int4*)(A + (size_t)(i0 + r) * 128 + half * 64);
    int4* da = (int4*)(shA + r * 136 + half * 64);
    const int4* sb = (const int4*)(B + (size_t)(j0 + r) * 128 + half * 64);
    int4* db = (int4*)(shB + r * 136 + half * 64);
#pragma unroll
    for (int q = 0; q < 8; ++q) { da[q] = sa[q]; db[q] = sb[q]; }
  }
  __syncthreads();
  const int wm = wv >> 1, wn = wv & 1;
  f32x4 acc[4][4];
  const f32x4 zz4 = {0.f, 0.f, 0.f, 0.f};
#pragma unroll
  for (int a = 0; a < 4; ++a)
#pragma unroll
    for (int b = 0; b < 4; ++b) acc[a][b] = zz4;
#pragma unroll
  for (int kk = 0; kk < 4; ++kk) {
    s16x8 af[4], bfr[4];
#pragma unroll
    for (int mt = 0; mt < 4; ++mt)
      af[mt] = *(const s16x8*)(shA + (wm * 64 + mt * 16 + l16) * 136 + kk * 32 + quad * 8);
#pragma unroll
    for (int nt = 0; nt < 4; ++nt)
      bfr[nt] = *(const s16x8*)(shB + (wn * 64 + nt * 16 + l16) * 136 + kk * 32 + quad * 8);
#pragma unroll
    for (int mt = 0; mt < 4; ++mt)
#pragma unroll
      for (int nt = 0; nt < 4; ++nt) acc[mt][nt] = mfma16(af[mt], bfr[nt], acc[mt][nt]);
  }
  float ra[4][4];
#pragma unroll
  for (int mt = 0; mt < 4; ++mt)
#pragma unroll
    for (int i = 0; i < 4; ++i) ra[mt][i] = rnA[i0 + wm * 64 + mt * 16 + quad * 4 + i];
#pragma unroll
  for (int nt = 0; nt < 4; ++nt) {
    int col = j0 + wn * 64 + nt * 16 + l16;
    float rb = rnB[col];
#pragma unroll
    for (int mt = 0; mt < 4; ++mt)
#pragma unroll
      for (int i = 0; i < 4; ++i) {
        int row = i0 + wm * 64 + mt * 16 + quad * 4 + i;
        C[(size_t)row * 4096 + col] = acc[mt][nt][i] * ra[mt][i] * rb;
      }
  }
}

// ---------------------------------------------------------------- topK + scatter
__launch_bounds__(256, 1)
__global__ void topk_scatter(const float* __restrict__ sim, const float* __restrict__ g,
                             float* __restrict__ concept, int* __restrict__ touched)
{
  __shared__ float shv[4096];
  __shared__ float shk[4096];
  __shared__ float red_v[4];
  __shared__ int   red_i[4];
  __shared__ int   selj[20];
  __shared__ float selv[20];
  __shared__ float gs[128];
  const int tid = threadIdx.x;
  const int row = blockIdx.x;
  const int l = tid & 63, wv = tid >> 6;
  for (int c4 = tid; c4 < 1024; c4 += 256) {
    float4 v = *(const float4*)(sim + (size_t)row * 4096 + c4 * 4);
    ((float4*)shv)[c4] = v;
    float4 k;
    k.x = (c4 * 4 + 0 == row) ? -1.f : fabsf(v.x);
    k.y = (c4 * 4 + 1 == row) ? -1.f : fabsf(v.y);
    k.z = (c4 * 4 + 2 == row) ? -1.f : fabsf(v.z);
    k.w = (c4 * 4 + 3 == row) ? -1.f : fabsf(v.w);
    ((float4*)shk)[c4] = k;
  }
  if (tid < 128) gs[tid] = g[(size_t)row * 128 + tid];
  __syncthreads();
  for (int it = 0; it < 20; ++it) {
    float best = -2.f; int bidx = 0;
    for (int c4 = tid; c4 < 1024; c4 += 256) {
      float4 k = ((const float4*)shk)[c4];
      int base = c4 * 4;
      if (k.x > best) { best = k.x; bidx = base; }
      if (k.y > best) { best = k.y; bidx = base + 1; }
      if (k.z > best) { best = k.z; bidx = base + 2; }
      if (k.w > best) { best = k.w; bidx = base + 3; }
    }
#pragma unroll
    for (int off = 32; off >= 1; off >>= 1) {   // ties -> lower index (jax top_k order)
      float ov = __shfl_down(best, off);
      int   oi = __shfl_down(bidx, off);
      if (ov > best || (ov == best && oi < bidx)) { best = ov; bidx = oi; }
    }
    if (l == 0) { red_v[wv] = best; red_i[wv] = bidx; }
    __syncthreads();
    if (tid == 0) {
      float bv = red_v[0]; int bj = red_i[0];
#pragma unroll
      for (int q = 1; q < 4; ++q)
        if (red_v[q] > bv || (red_v[q] == bv && red_i[q] < bj)) { bv = red_v[q]; bj = red_i[q]; }
      selj[it] = bj; selv[it] = shv[bj];
      shk[bj] = -2.f;
    }
    __syncthreads();
  }
  for (int idx = tid; idx < 20 * 128; idx += 256) {
    int it = idx >> 7, d = idx & 127;
    atomicAdd(concept + (size_t)selj[it] * 128 + d, selv[it] * gs[d]);
  }
  if (tid < 20) atomicOr(touched + selj[tid], 1);
}

// ---------------------------------------------------------------- diag add + valid
__global__ void diag_valid(const float* __restrict__ sim, const float* __restrict__ g,
                           const int* __restrict__ touched, float* __restrict__ concept,
                           float* __restrict__ valid)
{
  const int j = blockIdx.x, tid = threadIdx.x;
  const int l = tid & 63, wv = tid >> 6;
  __shared__ float ds[2];
  float cv = concept[(size_t)j * 128 + tid];
  if (touched[j]) cv += sim[(size_t)j * 4096 + j] * g[(size_t)j * 128 + tid];
  concept[(size_t)j * 128 + tid] = cv;
  float s = cv;
#pragma unroll
  for (int off = 32; off >= 1; off >>= 1) s += __shfl_down(s, off);
  if (l == 0) ds[wv] = s;
  __syncthreads();
  if (tid == 0) valid[j] = ((ds[0] + ds[1]) != 0.f) ? 1.f : 0.f;
}

// ---------------------------------------------------------------- cf = lrelu(concept@Whc.T+b)*valid
__global__ void cf_kernel(const float* __restrict__ concept, const float* __restrict__ Whc,
                          const float* __restrict__ bhc, const float* __restrict__ valid,
                          float* __restrict__ cf)
{
  int idx = blockIdx.x * 256 + threadIdx.x;
  int j = idx >> 7, o = idx & 127;
  const float4* cr = (const float4*)(concept + (size_t)j * 128);
  const float4* wr = (const float4*)(Whc + (size_t)o * 128);
  float s = bhc[o];
#pragma unroll 8
  for (int q = 0; q < 32; ++q) {
    float4 a = cr[q], b = wr[q];
    s += a.x * b.x + a.y * b.y + a.z * b.z + a.w * b.w;
  }
  cf[idx] = lrelu(s) * valid[j];
}

// ---------------------------------------------------------------- column softmax stats
__global__ void colstats(const float* __restrict__ s2, float* __restrict__ mcol,
                         float* __restrict__ rzcol)
{
  __shared__ float red[256];
  __shared__ float shm[16];
  const int tid = threadIdx.x;
  const int tx = tid & 15, ty = tid >> 4;
  const int j = blockIdx.x * 16 + tx;
  float mx = -1e30f;
  for (int r = ty; r < 4096; r += 16) mx = fmaxf(mx, s2[(size_t)r * 4096 + j]);
  red[tid] = mx;
  __syncthreads();
  if (ty == 0) {
    float m = red[tx];
    for (int q = 1; q < 16; ++q) m = fmaxf(m, red[q * 16 + tx]);
    shm[tx] = m;
  }
  __syncthreads();
  float m = shm[tx];
  float sm = 0.f;
  for (int r = ty; r < 4096; r += 16) sm += __expf(s2[(size_t)r * 4096 + j] - m);
  red[tid] = sm;
  __syncthreads();
  if (ty == 0) {
    float z = 0.f;
    for (int q = 0; q < 16; ++q) z += red[q * 16 + tx];
    mcol[j] = m;
    rzcol[j] = 1.f / z;   // z >= 1 always
  }
}

// ---------------------------------------------------------------- attn = exp(s-m)/Z -> bf16
__global__ void attn_cvt(const float* __restrict__ s2, const float* __restrict__ mcol,
                         const float* __restrict__ rzcol, u16* __restrict__ attn)
{
  size_t gid = (size_t)blockIdx.x * 256 + threadIdx.x;
  size_t rowi = gid >> 10;
  int c4 = (int)(gid & 1023) * 4;
  float4 s = *(const float4*)(s2 + rowi * 4096 + c4);
  float4 m = *(const float4*)(mcol + c4);
  float4 rz = *(const float4*)(rzcol + c4);
  ushort4 o;
  o.x = f2bf(__expf(s.x - m.x) * rz.x);
  o.y = f2bf(__expf(s.y - m.y) * rz.y);
  o.z = f2bf(__expf(s.z - m.z) * rz.z);
  o.w = f2bf(__expf(s.w - m.w) * rz.w);
  *(ushort4*)(attn + rowi * 4096 + c4) = o;
}

// ---------------------------------------------------------------- hs_pre = attn @ cf
__launch_bounds__(256, 1)
__global__ void attn_cf(const u16* __restrict__ attn, const u16* __restrict__ cfT,
                        float* __restrict__ hs_pre)
{
  __shared__ u16 shw[16 * 136];
  const int tid = threadIdx.x;
  const int l = tid & 63, wv = tid >> 6;
  const int quad = l >> 4, l16 = l & 15;
  const int r0 = blockIdx.x * 16;
  f32x4 acc[2];
  const f32x4 zz4 = {0.f, 0.f, 0.f, 0.f};
  acc[0] = zz4; acc[1] = zz4;
  for (int kc = 0; kc < 32; ++kc) {
    if (kc) __syncthreads();
    {
      int r = tid >> 4, seg = tid & 15;
      *(int4*)(shw + r * 136 + seg * 8) =
        *(const int4*)(attn + (size_t)(r0 + r) * 4096 + kc * 128 + seg * 8);
    }
    __syncthreads();
#pragma unroll
    for (int kk = 0; kk < 4; ++kk) {
      s16x8 a = *(const s16x8*)(shw + l16 * 136 + kk * 32 + quad * 8);
#pragma unroll
      for (int nt = 0; nt < 2; ++nt) {
        int n = wv * 32 + nt * 16 + l16;
        s16x8 b = *(const s16x8*)(cfT + (size_t)n * 4096 + kc * 128 + kk * 32 + quad * 8);
        acc[nt] = mfma16(a, b, acc[nt]);
      }
    }
  }
#pragma unroll
  for (int nt = 0; nt < 2; ++nt)
#pragma unroll
    for (int i = 0; i < 4; ++i) {
      int row = r0 + quad * 4 + i;
      int col = wv * 32 + nt * 16 + l16;
      hs_pre[(size_t)row * 128 + col] = acc[nt][i];
    }
}

// ---------------------------------------------------------------- head chain
__device__ void head_mm(const float* __restrict__ gW, const float* __restrict__ gb,
                        const float* in, float* out, float* shW, int tid)
{
  __syncthreads();
  for (int idx = tid; idx < 4096; idx += 256)
    ((float4*)shW)[idx] = ((const float4*)gW)[idx];
  __syncthreads();
  for (int it = 0; it < 8; ++it) {
    int idx = it * 256 + tid;
    int j = idx >> 7, o = idx & 127;
    float s = gb[o];
    const float* ir = in + j * 132;
    const float* wr = shW + o * 128;
#pragma unroll 8
    for (int k = 0; k < 128; k += 4) {
      float4 a = *(const float4*)(ir + k);
      float4 b = *(const float4*)(wr + k);
      s += a.x * b.x + a.y * b.y + a.z * b.z + a.w * b.w;
    }
    out[j * 132 + o] = lrelu(s);
  }
}

__launch_bounds__(256, 1)
__global__ void head_kernel(const float* __restrict__ hs_pre, const float* __restrict__ g,
                            const float* __restrict__ W_hs, const float* __restrict__ b_hs,
                            const float* __restrict__ W_fore, const float* __restrict__ b_fore,
                            const float* __restrict__ W_back, const float* __restrict__ b_back,
                            const float* __restrict__ W_indi, const float* __restrict__ b_indi,
                            const float* __restrict__ W_out, const float* __restrict__ b_out,
                            float* __restrict__ outp)
{
  __shared__ float shW[128 * 128];
  __shared__ float bufA[16 * 132];
  __shared__ float bufB[16 * 132];
  __shared__ float bufC[16 * 132];
  __shared__ float bufD[16 * 132];
  const int tid = threadIdx.x;
  const int r0 = blockIdx.x * 16;
  for (int idx = tid; idx < 512; idx += 256) {
    int j = idx >> 5, q = idx & 31;
    *(float4*)(bufA + j * 132 + q * 4) = *(const float4*)(hs_pre + (size_t)(r0 + j) * 128 + q * 4);
  }
  head_mm(W_hs,   b_hs,   bufA, bufB, shW, tid);   // hs
  head_mm(W_back, b_back, bufB, bufC, shW, tid);   // back
  head_mm(W_fore, b_fore, bufB, bufD, shW, tid);   // fore
  __syncthreads();
  for (int idx = tid; idx < 2048; idx += 256) {
    int j = idx >> 7, d = idx & 127;
    bufA[j * 132 + d] = g[(size_t)(r0 + j) * 128 + d] - bufC[j * 132 + d];
  }
  head_mm(W_indi, b_indi, bufA, bufC, shW, tid);   // indi
  __syncthreads();
  if (tid < 16) {
    float s = b_out[0];
    const float* fr = bufD + tid * 132;
    const float* ir = bufC + tid * 132;
    for (int d = 0; d < 128; ++d) s += (fr[d] + ir[d]) * W_out[d];
    outp[r0 + tid] = s;
  }
}

// ---------------------------------------------------------------- launch
// Workspace layout (bytes). Region A is reused: h0_seq bf16 (64MiB) -> sim fp32
// (64MiB) -> s2 fp32 (stage-ordered, no overlap in time).
static const size_t OFF_A       = 0;             // 67,108,864
static const size_t OFF_ATTN    = 67108864;      // 33,554,432  attn bf16
static const size_t OFF_G       = 100663296;     //  2,097,152  g fp32
static const size_t OFF_GBF     = 102760448;     //  1,048,576  g bf16
static const size_t OFF_RNG     = 103809024;     //     16,384  1/|g_i|
static const size_t OFF_CONCEPT = 103825408;     //  2,097,152
static const size_t OFF_TOUCH   = 105922560;     //     16,384  (memset with concept)
static const size_t OFF_VALID   = 105938944;     //     16,384
static const size_t OFF_CF      = 105955328;     //  2,097,152
static const size_t OFF_CFBF    = 108052480;     //  1,048,576
static const size_t OFF_CFT     = 109101056;     //  1,048,576  cf^T bf16 [128][4096]
static const size_t OFF_RNCF    = 110149632;     //     16,384
static const size_t OFF_MCOL    = 110166016;     //     16,384
static const size_t OFF_RZ      = 110182400;     //     16,384
static const size_t OFF_HSPRE   = 110198784;     //  2,097,152
static const size_t OFF_WIH0    = 112295936;     //     24,576
static const size_t OFF_WHH0    = 112320512;     //     98,304
static const size_t OFF_WIH1    = 112418816;     //     98,304
static const size_t OFF_WHH1    = 112517120;     //     98,304  -> end 112,615,424

extern "C" void kernel_launch(void* const* d_in, const int* in_sizes, int n_in,
                              void* d_out, int out_size, void* d_ws, size_t ws_size,
                              hipStream_t stream)
{
  (void)in_sizes; (void)n_in; (void)out_size; (void)ws_size;
  const float* x      = (const float*)d_in[0];
  const float* Wih0   = (const float*)d_in[1];
  const float* Whh0   = (const float*)d_in[2];
  const float* bih0   = (const float*)d_in[3];
  const float* bhh0   = (const float*)d_in[4];
  const float* Wih1   = (const float*)d_in[5];
  const float* Whh1   = (const float*)d_in[6];
  const float* bih1   = (const float*)d_in[7];
  const float* bhh1   = (const float*)d_in[8];
  const float* W_hc   = (const float*)d_in[9];
  const float* b_hc   = (const float*)d_in[10];
  const float* W_hs   = (const float*)d_in[11];
  const float* b_hs   = (const float*)d_in[12];
  const float* W_fore = (const float*)d_in[13];
  const float* b_fore = (const float*)d_in[14];
  const float* W_back = (const float*)d_in[15];
  const float* b_back = (const float*)d_in[16];
  const float* W_indi = (const float*)d_in[17];
  const float* b_indi = (const float*)d_in[18];
  const float* W_out  = (const float*)d_in[19];
  const float* b_out  = (const float*)d_in[20];

  char* ws = (char*)d_ws;
  u16*   hseq    = (u16*)(ws + OFF_A);
  float* simbuf  = (float*)(ws + OFF_A);
  u16*   attnb   = (u16*)(ws + OFF_ATTN);
  float* gbuf    = (float*)(ws + OFF_G);
  u16*   gbf     = (u16*)(ws + OFF_GBF);
  float* rng     = (float*)(ws + OFF_RNG);
  float* concept = (float*)(ws + OFF_CONCEPT);
  int*   touched = (int*)(ws + OFF_TOUCH);
  float* valid   = (float*)(ws + OFF_VALID);
  float* cf      = (float*)(ws + OFF_CF);
  u16*   cfbf    = (u16*)(ws + OFF_CFBF);
  u16*   cfT     = (u16*)(ws + OFF_CFT);
  float* rncf    = (float*)(ws + OFF_RNCF);
  float* mcol    = (float*)(ws + OFF_MCOL);
  float* rzcol   = (float*)(ws + OFF_RZ);
  float* hs_pre  = (float*)(ws + OFF_HSPRE);
  u16*   wih0b   = (u16*)(ws + OFF_WIH0);
  u16*   whh0b   = (u16*)(ws + OFF_WHH0);
  u16*   wih1b   = (u16*)(ws + OFF_WIH1);
  u16*   whh1b   = (u16*)(ws + OFF_WHH1);

  cvt_bf16<<<48,  256, 0, stream>>>(Wih0, wih0b, 12288);
  cvt_bf16<<<192, 256, 0, stream>>>(Whh0, whh0b, 49152);
  cvt_bf16<<<192, 256, 0, stream>>>(Wih1, wih1b, 49152);
  cvt_bf16<<<192, 256, 0, stream>>>(Whh1, whh1b, 49152);

  gru_kernel<0><<<256, 512, 0, stream>>>((const void*)x, wih0b, whh0b, bih0, bhh0,
                                         hseq, (float*)nullptr);
  gru_kernel<1><<<256, 512, 0, stream>>>((const void*)hseq, wih1b, whh1b, bih1, bhh1,
                                         (u16*)nullptr, gbuf);

  norm_cvt<false><<<1024, 256, 0, stream>>>(gbuf, gbf, (u16*)nullptr, rng);
  cos_gemm<<<dim3(32, 32), 256, 0, stream>>>(gbf, gbf, rng, rng, simbuf);

  hipMemsetAsync(ws + OFF_CONCEPT, 0, 2097152 + 16384, stream);
  topk_scatter<<<4096, 256, 0, stream>>>(simbuf, gbuf, concept, touched);
  diag_valid<<<4096, 128, 0, stream>>>(simbuf, gbuf, touched, concept, valid);
  cf_kernel<<<2048, 256, 0, stream>>>(concept, W_hc, b_hc, valid, cf);
  norm_cvt<true><<<1024, 256, 0, stream>>>(cf, cfbf, cfT, rncf);

  cos_gemm<<<dim3(32, 32), 256, 0, stream>>>(gbf, cfbf, rng, rncf, simbuf);  // s2
  colstats<<<256, 256, 0, stream>>>(simbuf, mcol, rzcol);
  attn_cvt<<<16384, 256, 0, stream>>>(simbuf, mcol, rzcol, attnb);
  attn_cf<<<256, 256, 0, stream>>>(attnb, cfT, hs_pre);

  head_kernel<<<256, 256, 0, stream>>>(hs_pre, gbuf, W_hs, b_hs, W_fore, b_fore,
                                       W_back, b_back, W_indi, b_indi, W_out, b_out,
                                       (float*)d_out);
}

// Round 2
// 564.121 us; speedup vs baseline: 1.4657x; 1.4657x over previous
//
#include <hip/hip_runtime.h>

// SGA_75531294867605 — GRU x2 -> cos-sim topK concept graph -> softmax attention head.
// R2: (a) head_kernel rewritten as MFMA (R1 had 64-lane LDS bank conflicts, 154us);
//     (b) softmax pipeline fused: exp+colsum in cos_gemm<1> epilogue, 1/Z folded
//         into cf (colstats + attn_cvt kernels deleted, ~290MB HBM saved);
//     (c) all weight bf16 converts in one kernel.

typedef float f32x4 __attribute__((ext_vector_type(4)));
typedef short s16x8 __attribute__((ext_vector_type(8)));
typedef unsigned short u16;

#define DEVFN static __device__ __forceinline__

DEVFN u16 f2bf(float f) {
  union { float f; unsigned u; } v; v.f = f;
  return (u16)((v.u + 0x7FFFu + ((v.u >> 16) & 1u)) >> 16);  // RNE
}

DEVFN f32x4 mfma16(s16x8 a, s16x8 b, f32x4 c) {
  return __builtin_amdgcn_mfma_f32_16x16x32_bf16(a, b, c, 0, 0, 0);
}

DEVFN float sigmf(float x) { return __builtin_amdgcn_rcpf(1.f + __expf(-x)); }
DEVFN float tanhf_fast(float x) {
  float e = __expf(2.f * x);
  return 1.f - 2.f * __builtin_amdgcn_rcpf(e + 1.f);
}
DEVFN float lrelu(float v) { return v > 0.f ? v : 0.2f * v; }

// ---------------------------------------------------------------- all-weights fp32->bf16
// Dest arena (bf16 elem offsets): wih0 0 | whh0 12288 | wih1 61440 | whh1 110592 |
// whs 159744 | wfore 176128 | wback 192512 | windi 208896 | end 225280
__global__ void cvt_all(const float* __restrict__ w0, const float* __restrict__ w1,
                        const float* __restrict__ w2, const float* __restrict__ w3,
                        const float* __restrict__ w4, const float* __restrict__ w5,
                        const float* __restrict__ w6, const float* __restrict__ w7,
                        u16* __restrict__ dst) {
  int i = blockIdx.x * 256 + threadIdx.x;
  if (i >= 225280) return;
  float v;
  if      (i < 12288)  v = w0[i];
  else if (i < 61440)  v = w1[i - 12288];
  else if (i < 110592) v = w2[i - 61440];
  else if (i < 159744) v = w3[i - 110592];
  else if (i < 176128) v = w4[i - 159744];
  else if (i < 192512) v = w5[i - 176128];
  else if (i < 208896) v = w6[i - 192512];
  else                 v = w7[i - 208896];
  dst[i] = f2bf(v);
}

// ---------------------------------------------------------------- fused GRU layer
template<int LAYER>
__launch_bounds__(512, 1)
__global__ void gru_kernel(const void* __restrict__ xin,
                           const u16* __restrict__ Wih, const u16* __restrict__ Whh,
                           const float* __restrict__ bih, const float* __restrict__ bhh,
                           u16* __restrict__ hseq_out, float* __restrict__ g_out)
{
  constexpr int KIN = (LAYER == 0) ? 32 : 128;
  constexpr int NKK = KIN / 32;
  constexpr int XS  = (LAYER == 0) ? 40 : 136;
  const int tid  = threadIdx.x;
  const int w    = tid >> 6;
  const int l    = tid & 63;
  const int quad = l >> 4;
  const int l16  = l & 15;
  const int r0   = blockIdx.x * 16;
  const int c    = w * 16 + l16;

  __shared__ u16 sh_x[16 * XS];
  __shared__ u16 sh_hb[16 * 136];

  s16x8 Bih[3][NKK];
  s16x8 Bhh[3][4];
  float bi[3], bh[3];
#pragma unroll
  for (int g = 0; g < 3; ++g) {
    int j = g * 128 + c;
    bi[g] = bih[j];
    bh[g] = bhh[j];
#pragma unroll
    for (int kk = 0; kk < NKK; ++kk)
      Bih[g][kk] = *(const s16x8*)(Wih + j * KIN + kk * 32 + quad * 8);
#pragma unroll
    for (int kk = 0; kk < 4; ++kk)
      Bhh[g][kk] = *(const s16x8*)(Whh + j * 128 + kk * 32 + quad * 8);
  }
  float hreg[4] = {0.f, 0.f, 0.f, 0.f};
  for (int idx = tid; idx < 16 * 136; idx += 512) sh_hb[idx] = 0;

  for (int t = 0; t < 64; ++t) {
    if constexpr (LAYER == 0) {
      int r = tid >> 5, cc = tid & 31;
      float xv = ((const float*)xin)[(size_t)(r0 + r) * (64 * 32) + t * 32 + cc];
      sh_x[r * XS + cc] = f2bf(xv);
    } else {
      int r = tid >> 5, c4 = (tid & 31) * 4;
      *(ushort4*)(sh_x + r * XS + c4) =
        *(const ushort4*)((const u16*)xin + (size_t)(r0 + r) * (64 * 128) + t * 128 + c4);
    }
    __syncthreads();
    s16x8 ax[NKK], ah[4];
#pragma unroll
    for (int kk = 0; kk < NKK; ++kk)
      ax[kk] = *(const s16x8*)(sh_x + l16 * XS + kk * 32 + quad * 8);
#pragma unroll
    for (int kk = 0; kk < 4; ++kk)
      ah[kk] = *(const s16x8*)(sh_hb + l16 * 136 + kk * 32 + quad * 8);
    __syncthreads();

    f32x4 ai[3], ahh[3];
    const f32x4 zz4 = {0.f, 0.f, 0.f, 0.f};
#pragma unroll
    for (int g = 0; g < 3; ++g) { ai[g] = zz4; ahh[g] = zz4; }
#pragma unroll
    for (int g = 0; g < 3; ++g)
#pragma unroll
      for (int kk = 0; kk < NKK; ++kk) ai[g] = mfma16(ax[kk], Bih[g][kk], ai[g]);
#pragma unroll
    for (int g = 0; g < 3; ++g)
#pragma unroll
      for (int kk = 0; kk < 4; ++kk)  ahh[g] = mfma16(ah[kk], Bhh[g][kk], ahh[g]);

#pragma unroll
    for (int i = 0; i < 4; ++i) {
      int m = quad * 4 + i;
      float rr = sigmf(ai[0][i] + bi[0] + ahh[0][i] + bh[0]);
      float zg = sigmf(ai[1][i] + bi[1] + ahh[1][i] + bh[1]);
      float nn = tanhf_fast(ai[2][i] + bi[2] + rr * (ahh[2][i] + bh[2]));
      float hnew = (1.f - zg) * nn + zg * hreg[i];
      hreg[i] = hnew;
      u16 hb = f2bf(hnew);
      sh_hb[m * 136 + c] = hb;
      if constexpr (LAYER == 0) {
        hseq_out[(size_t)(r0 + m) * (64 * 128) + t * 128 + c] = hb;
      } else {
        if (t == 63) g_out[(size_t)(r0 + m) * 128 + c] = hnew;
      }
    }
  }
}

// ---------------------------------------------------------------- row norms + bf16
__global__ void norm_cvt(const float* __restrict__ src, u16* __restrict__ dst,
                         float* __restrict__ rn)
{
  const int tid = threadIdx.x;
  const int wv = tid >> 6, l = tid & 63;
  const int row = blockIdx.x * 4 + wv;
  float2 f2 = *(const float2*)(src + (size_t)row * 128 + l * 2);
  float s = f2.x * f2.x + f2.y * f2.y;
#pragma unroll
  for (int off = 32; off >= 1; off >>= 1) s += __shfl_xor(s, off);
  ushort2 p; p.x = f2bf(f2.x); p.y = f2bf(f2.y);
  *(ushort2*)(dst + (size_t)row * 128 + l * 2) = p;
  if (l == 0) rn[row] = (s == 0.f) ? 0.f : rsqrtf(s);
}

// ---------------------------------------------------------------- cos-sim GEMM
// MODE 0: C[i][j] = (A_i.B_j)*rnA[i]*rnB[j] fp32.
// MODE 1: e = exp(cos) -> bf16 attn numerator + per-column sums (softmax w/o
//         max-sub: cos in [-1,1], exp cannot overflow; identical math).
template<int MODE>
__launch_bounds__(256, 1)
__global__ void cos_gemm(const u16* __restrict__ A, const u16* __restrict__ B,
                         const float* __restrict__ rnA, const float* __restrict__ rnB,
                         float* __restrict__ C, u16* __restrict__ E,
                         float* __restrict__ colsum)
{
  __shared__ u16 shA[128 * 136];
  __shared__ u16 shB[128 * 136];
  const int tid = threadIdx.x;
  const int l = tid & 63, wv = tid >> 6;
  const int quad = l >> 4, l16 = l & 15;
  const int i0 = blockIdx.y * 128, j0 = blockIdx.x * 128;
  {
    int r = tid >> 1, half = tid & 1;
    const int4* sa = (const int4*)(A + (size_t)(i0 + r) * 128 + half * 64);
    int4* da = (int4*)(shA + r * 136 + half * 64);
    const int4* sb = (const int4*)(B + (size_t)(j0 + r) * 128 + half * 64);
    int4* db = (int4*)(shB + r * 136 + half * 64);
#pragma unroll
    for (int q = 0; q < 8; ++q) { da[q] = sa[q]; db[q] = sb[q]; }
  }
  __syncthreads();
  const int wm = wv >> 1, wn = wv & 1;
  f32x4 acc[4][4];
  const f32x4 zz4 = {0.f, 0.f, 0.f, 0.f};
#pragma unroll
  for (int a = 0; a < 4; ++a)
#pragma unroll
    for (int b = 0; b < 4; ++b) acc[a][b] = zz4;
#pragma unroll
  for (int kk = 0; kk < 4; ++kk) {
    s16x8 af[4], bfr[4];
#pragma unroll
    for (int mt = 0; mt < 4; ++mt)
      af[mt] = *(const s16x8*)(shA + (wm * 64 + mt * 16 + l16) * 136 + kk * 32 + quad * 8);
#pragma unroll
    for (int nt = 0; nt < 4; ++nt)
      bfr[nt] = *(const s16x8*)(shB + (wn * 64 + nt * 16 + l16) * 136 + kk * 32 + quad * 8);
#pragma unroll
    for (int mt = 0; mt < 4; ++mt)
#pragma unroll
      for (int nt = 0; nt < 4; ++nt) acc[mt][nt] = mfma16(af[mt], bfr[nt], acc[mt][nt]);
  }
  float ra[4][4];
#pragma unroll
  for (int mt = 0; mt < 4; ++mt)
#pragma unroll
    for (int i = 0; i < 4; ++i) ra[mt][i] = rnA[i0 + wm * 64 + mt * 16 + quad * 4 + i];
#pragma unroll
  for (int nt = 0; nt < 4; ++nt) {
    int col = j0 + wn * 64 + nt * 16 + l16;
    float rb = rnB[col];
    float psum = 0.f;
#pragma unroll
    for (int mt = 0; mt < 4; ++mt)
#pragma unroll
      for (int i = 0; i < 4; ++i) {
        int row = i0 + wm * 64 + mt * 16 + quad * 4 + i;
        float v = acc[mt][nt][i] * ra[mt][i] * rb;
        if constexpr (MODE == 0) {
          C[(size_t)row * 4096 + col] = v;
        } else {
          float e = __expf(v);
          E[(size_t)row * 4096 + col] = f2bf(e);
          psum += e;
        }
      }
    if constexpr (MODE == 1) {
      psum += __shfl_xor(psum, 16);        // lanes sharing l16 across quads = same col
      psum += __shfl_xor(psum, 32);
      if (quad == 0) atomicAdd(colsum + col, psum);
    }
  }
}

// ---------------------------------------------------------------- topK + scatter
__launch_bounds__(256, 1)
__global__ void topk_scatter(const float* __restrict__ sim, const float* __restrict__ g,
                             float* __restrict__ concept, int* __restrict__ touched)
{
  __shared__ float shv[4096];
  __shared__ float shk[4096];
  __shared__ float red_v[4];
  __shared__ int   red_i[4];
  __shared__ int   selj[20];
  __shared__ float selv[20];
  __shared__ float gs[128];
  const int tid = threadIdx.x;
  const int row = blockIdx.x;
  const int l = tid & 63, wv = tid >> 6;
  for (int c4 = tid; c4 < 1024; c4 += 256) {
    float4 v = *(const float4*)(sim + (size_t)row * 4096 + c4 * 4);
    ((float4*)shv)[c4] = v;
    float4 k;
    k.x = (c4 * 4 + 0 == row) ? -1.f : fabsf(v.x);
    k.y = (c4 * 4 + 1 == row) ? -1.f : fabsf(v.y);
    k.z = (c4 * 4 + 2 == row) ? -1.f : fabsf(v.z);
    k.w = (c4 * 4 + 3 == row) ? -1.f : fabsf(v.w);
    ((float4*)shk)[c4] = k;
  }
  if (tid < 128) gs[tid] = g[(size_t)row * 128 + tid];
  __syncthreads();
  for (int it = 0; it < 20; ++it) {
    float best = -2.f; int bidx = 0;
    for (int c4 = tid; c4 < 1024; c4 += 256) {
      float4 k = ((const float4*)shk)[c4];
      int base = c4 * 4;
      if (k.x > best) { best = k.x; bidx = base; }
      if (k.y > best) { best = k.y; bidx = base + 1; }
      if (k.z > best) { best = k.z; bidx = base + 2; }
      if (k.w > best) { best = k.w; bidx = base + 3; }
    }
#pragma unroll
    for (int off = 32; off >= 1; off >>= 1) {
      float ov = __shfl_down(best, off);
      int   oi = __shfl_down(bidx, off);
      if (ov > best || (ov == best && oi < bidx)) { best = ov; bidx = oi; }
    }
    if (l == 0) { red_v[wv] = best; red_i[wv] = bidx; }
    __syncthreads();
    if (tid == 0) {
      float bv = red_v[0]; int bj = red_i[0];
#pragma unroll
      for (int q = 1; q < 4; ++q)
        if (red_v[q] > bv || (red_v[q] == bv && red_i[q] < bj)) { bv = red_v[q]; bj = red_i[q]; }
      selj[it] = bj; selv[it] = shv[bj];
      shk[bj] = -2.f;
    }
    __syncthreads();
  }
  for (int idx = tid; idx < 20 * 128; idx += 256) {
    int it = idx >> 7, d = idx & 127;
    atomicAdd(concept + (size_t)selj[it] * 128 + d, selv[it] * gs[d]);
  }
  if (tid < 20) atomicOr(touched + selj[tid], 1);
}

// ---------------------------------------------------------------- diag add + valid
__global__ void diag_valid(const float* __restrict__ sim, const float* __restrict__ g,
                           const int* __restrict__ touched, float* __restrict__ concept,
                           float* __restrict__ valid)
{
  const int j = blockIdx.x, tid = threadIdx.x;
  const int l = tid & 63, wv = tid >> 6;
  __shared__ float ds[2];
  float cv = concept[(size_t)j * 128 + tid];
  if (touched[j]) cv += sim[(size_t)j * 4096 + j] * g[(size_t)j * 128 + tid];
  concept[(size_t)j * 128 + tid] = cv;
  float s = cv;
#pragma unroll
  for (int off = 32; off >= 1; off >>= 1) s += __shfl_down(s, off);
  if (l == 0) ds[wv] = s;
  __syncthreads();
  if (tid == 0) valid[j] = ((ds[0] + ds[1]) != 0.f) ? 1.f : 0.f;
}

// ---------------------------------------------------------------- cf = lrelu(concept@Whc.T+b)*valid
__global__ void cf_kernel(const float* __restrict__ concept, const float* __restrict__ Whc,
                          const float* __restrict__ bhc, const float* __restrict__ valid,
                          float* __restrict__ cf)
{
  int idx = blockIdx.x * 256 + threadIdx.x;
  int j = idx >> 7, o = idx & 127;
  const float4* cr = (const float4*)(concept + (size_t)j * 128);
  const float4* wr = (const float4*)(Whc + (size_t)o * 128);
  float s = bhc[o];
#pragma unroll 8
  for (int q = 0; q < 32; ++q) {
    float4 a = cr[q], b = wr[q];
    s += a.x * b.x + a.y * b.y + a.z * b.z + a.w * b.w;
  }
  cf[idx] = lrelu(s) * valid[j];
}

// ---------------------------------------------------------------- cfTs[n][c] = bf16(cf[c][n]/Z[c])
__global__ void scale_cfT(const float* __restrict__ cf, const float* __restrict__ colsum,
                          u16* __restrict__ cfTs)
{
  int idx = blockIdx.x * 256 + threadIdx.x;   // 128*4096
  int n = idx >> 12, c = idx & 4095;
  float rz = __builtin_amdgcn_rcpf(colsum[c]);
  cfTs[idx] = f2bf(cf[(size_t)c * 128 + n] * rz);
}

// ---------------------------------------------------------------- hs_pre = E @ cfTs.T
__launch_bounds__(256, 1)
__global__ void attn_cf(const u16* __restrict__ attn, const u16* __restrict__ cfT,
                        float* __restrict__ hs_pre)
{
  __shared__ u16 shw[16 * 136];
  const int tid = threadIdx.x;
  const int l = tid & 63, wv = tid >> 6;
  const int quad = l >> 4, l16 = l & 15;
  const int r0 = blockIdx.x * 16;
  f32x4 acc[2];
  const f32x4 zz4 = {0.f, 0.f, 0.f, 0.f};
  acc[0] = zz4; acc[1] = zz4;
  for (int kc = 0; kc < 32; ++kc) {
    if (kc) __syncthreads();
    {
      int r = tid >> 4, seg = tid & 15;
      *(int4*)(shw + r * 136 + seg * 8) =
        *(const int4*)(attn + (size_t)(r0 + r) * 4096 + kc * 128 + seg * 8);
    }
    __syncthreads();
#pragma unroll
    for (int kk = 0; kk < 4; ++kk) {
      s16x8 a = *(const s16x8*)(shw + l16 * 136 + kk * 32 + quad * 8);
#pragma unroll
      for (int nt = 0; nt < 2; ++nt) {
        int n = wv * 32 + nt * 16 + l16;
        s16x8 b = *(const s16x8*)(cfT + (size_t)n * 4096 + kc * 128 + kk * 32 + quad * 8);
        acc[nt] = mfma16(a, b, acc[nt]);
      }
    }
  }
#pragma unroll
  for (int nt = 0; nt < 2; ++nt)
#pragma unroll
    for (int i = 0; i < 4; ++i) {
      int row = r0 + quad * 4 + i;
      int col = wv * 32 + nt * 16 + l16;
      hs_pre[(size_t)row * 128 + col] = acc[nt][i];
    }
}

// ---------------------------------------------------------------- head: MFMA chain
// Block = 16 rows, 4 waves; wave wv owns cols [32wv,32wv+32). B-frags straight from
// bf16 weights in global (L2-hot, identical across blocks). A staged in LDS +8 pad.
__launch_bounds__(256, 1)
__global__ void head_kernel(const float* __restrict__ hs_pre, const float* __restrict__ g,
                            const u16* __restrict__ whs, const u16* __restrict__ wfore,
                            const u16* __restrict__ wback, const u16* __restrict__ windi,
                            const float* __restrict__ b_hs, const float* __restrict__ b_fore,
                            const float* __restrict__ b_back, const float* __restrict__ b_indi,
                            const float* __restrict__ W_out, const float* __restrict__ b_out,
                            float* __restrict__ outp)
{
  __shared__ u16 bufin[16 * 136];
  __shared__ u16 bufB[16 * 136];
  __shared__ float bufF[16 * 132];
  __shared__ float shWout[128];
  const int tid = threadIdx.x;
  const int l = tid & 63, wv = tid >> 6;
  const int quad = l >> 4, l16 = l & 15;
  const int r0 = blockIdx.x * 16;
  const f32x4 zz4 = {0.f, 0.f, 0.f, 0.f};

  if (tid < 128) shWout[tid] = W_out[tid];
  for (int idx = tid; idx < 2048; idx += 256) {
    int j = idx >> 7, n = idx & 127;
    bufin[j * 136 + n] = f2bf(hs_pre[(size_t)(r0 + j) * 128 + n]);
  }
  __syncthreads();
  // mm1: hs = lrelu(hs_pre @ W_hs.T + b_hs)
  {
    s16x8 a[4];
#pragma unroll
    for (int kk = 0; kk < 4; ++kk)
      a[kk] = *(const s16x8*)(bufin + l16 * 136 + kk * 32 + quad * 8);
    f32x4 acc[2]; acc[0] = zz4; acc[1] = zz4;
#pragma unroll
    for (int nt = 0; nt < 2; ++nt) {
      int n = wv * 32 + nt * 16 + l16;
#pragma unroll
      for (int kk = 0; kk < 4; ++kk)
        acc[nt] = mfma16(a[kk], *(const s16x8*)(whs + n * 128 + kk * 32 + quad * 8), acc[nt]);
    }
#pragma unroll
    for (int nt = 0; nt < 2; ++nt) {
      int n = wv * 32 + nt * 16 + l16;
      float bb = b_hs[n];
#pragma unroll
      for (int i = 0; i < 4; ++i)
        bufB[(quad * 4 + i) * 136 + n] = f2bf(lrelu(acc[nt][i] + bb));
    }
  }
  __syncthreads();
  // mm2+3: fore -> bufF (fp32); back -> bufin = bf16(g - back)
  {
    s16x8 a[4];
#pragma unroll
    for (int kk = 0; kk < 4; ++kk)
      a[kk] = *(const s16x8*)(bufB + l16 * 136 + kk * 32 + quad * 8);
    f32x4 aF[2], aB[2]; aF[0] = zz4; aF[1] = zz4; aB[0] = zz4; aB[1] = zz4;
#pragma unroll
    for (int nt = 0; nt < 2; ++nt) {
      int n = wv * 32 + nt * 16 + l16;
#pragma unroll
      for (int kk = 0; kk < 4; ++kk) {
        aF[nt] = mfma16(a[kk], *(const s16x8*)(wfore + n * 128 + kk * 32 + quad * 8), aF[nt]);
        aB[nt] = mfma16(a[kk], *(const s16x8*)(wback + n * 128 + kk * 32 + quad * 8), aB[nt]);
      }
    }
#pragma unroll
    for (int nt = 0; nt < 2; ++nt) {
      int n = wv * 32 + nt * 16 + l16;
      float bf_ = b_fore[n], bb_ = b_back[n];
#pragma unroll
      for (int i = 0; i < 4; ++i) {
        int m = quad * 4 + i;
        bufF[m * 132 + n] = lrelu(aF[nt][i] + bf_);
        float back = lrelu(aB[nt][i] + bb_);
        float gv = g[(size_t)(r0 + m) * 128 + n];
        bufin[m * 136 + n] = f2bf(gv - back);
      }
    }
  }
  __syncthreads();
  // mm4: indi; bufF += lrelu((g-back)@W_indi.T + b_indi)  (same lane owns (m,n))
  {
    s16x8 a[4];
#pragma unroll
    for (int kk = 0; kk < 4; ++kk)
      a[kk] = *(const s16x8*)(bufin + l16 * 136 + kk * 32 + quad * 8);
    f32x4 acc[2]; acc[0] = zz4; acc[1] = zz4;
#pragma unroll
    for (int nt = 0; nt < 2; ++nt) {
      int n = wv * 32 + nt * 16 + l16;
#pragma unroll
      for (int kk = 0; kk < 4; ++kk)
        acc[nt] = mfma16(a[kk], *(const s16x8*)(windi + n * 128 + kk * 32 + quad * 8), acc[nt]);
    }
#pragma unroll
    for (int nt = 0; nt < 2; ++nt) {
      int n = wv * 32 + nt * 16 + l16;
      float bi_ = b_indi[n];
#pragma unroll
      for (int i = 0; i < 4; ++i)
        bufF[(quad * 4 + i) * 132 + n] += lrelu(acc[nt][i] + bi_);
    }
  }
  __syncthreads();
  if (tid < 16) {
    float s = b_out[0];
    const float* fr = bufF + tid * 132;
    for (int n = 0; n < 128; ++n) s += fr[n] * shWout[n];
    outp[r0 + tid] = s;
  }
}

// ---------------------------------------------------------------- workspace layout
static const size_t OFF_A       = 0;             // 67,108,864  hseq bf16 / sim fp32
static const size_t OFF_ATTN    = 67108864;      // 33,554,432  attn numerator bf16
static const size_t OFF_G       = 100663296;     //  2,097,152  g fp32
static const size_t OFF_GBF     = 102760448;     //  1,048,576
static const size_t OFF_RNG     = 103809024;     //     16,384
static const size_t OFF_CONCEPT = 103825408;     //  2,097,152
static const size_t OFF_TOUCH   = 105922560;     //     16,384
static const size_t OFF_COLSUM  = 105938944;     //     16,384  (memset w/ concept)
static const size_t OFF_VALID   = 105955328;     //     16,384
static const size_t OFF_CF      = 105971712;     //  2,097,152
static const size_t OFF_CFBF    = 108068864;     //  1,048,576
static const size_t OFF_CFTS    = 109117440;     //  1,048,576  cf^T/Z bf16 [128][4096]
static const size_t OFF_RNCF    = 110166016;     //     16,384
static const size_t OFF_HSPRE   = 110182400;     //  2,097,152
static const size_t OFF_WB      = 112279552;     //    450,560  bf16 weight arena

extern "C" void kernel_launch(void* const* d_in, const int* in_sizes, int n_in,
                              void* d_out, int out_size, void* d_ws, size_t ws_size,
                              hipStream_t stream)
{
  (void)in_sizes; (void)n_in; (void)out_size; (void)ws_size;
  const float* x      = (const float*)d_in[0];
  const float* Wih0   = (const float*)d_in[1];
  const float* Whh0   = (const float*)d_in[2];
  const float* bih0   = (const float*)d_in[3];
  const float* bhh0   = (const float*)d_in[4];
  const float* Wih1   = (const float*)d_in[5];
  const float* Whh1   = (const float*)d_in[6];
  const float* bih1   = (const float*)d_in[7];
  const float* bhh1   = (const float*)d_in[8];
  const float* W_hc   = (const float*)d_in[9];
  const float* b_hc   = (const float*)d_in[10];
  const float* W_hs   = (const float*)d_in[11];
  const float* b_hs   = (const float*)d_in[12];
  const float* W_fore = (const float*)d_in[13];
  const float* b_fore = (const float*)d_in[14];
  const float* W_back = (const float*)d_in[15];
  const float* b_back = (const float*)d_in[16];
  const float* W_indi = (const float*)d_in[17];
  const float* b_indi = (const float*)d_in[18];
  const float* W_out  = (const float*)d_in[19];
  const float* b_out  = (const float*)d_in[20];

  char* ws = (char*)d_ws;
  u16*   hseq    = (u16*)(ws + OFF_A);
  float* simbuf  = (float*)(ws + OFF_A);
  u16*   attnb   = (u16*)(ws + OFF_ATTN);
  float* gbuf    = (float*)(ws + OFF_G);
  u16*   gbf     = (u16*)(ws + OFF_GBF);
  float* rng     = (float*)(ws + OFF_RNG);
  float* concept = (float*)(ws + OFF_CONCEPT);
  int*   touched = (int*)(ws + OFF_TOUCH);
  float* colsum  = (float*)(ws + OFF_COLSUM);
  float* valid   = (float*)(ws + OFF_VALID);
  float* cf      = (float*)(ws + OFF_CF);
  u16*   cfbf    = (u16*)(ws + OFF_CFBF);
  u16*   cfTs    = (u16*)(ws + OFF_CFTS);
  float* rncf    = (float*)(ws + OFF_RNCF);
  float* hs_pre  = (float*)(ws + OFF_HSPRE);
  u16*   wsB     = (u16*)(ws + OFF_WB);
  u16 *wih0b = wsB, *whh0b = wsB + 12288, *wih1b = wsB + 61440, *whh1b = wsB + 110592;
  u16 *whsb = wsB + 159744, *wforeb = wsB + 176128, *wbackb = wsB + 192512, *windib = wsB + 208896;

  cvt_all<<<880, 256, 0, stream>>>(Wih0, Whh0, Wih1, Whh1, W_hs, W_fore, W_back, W_indi, wsB);

  gru_kernel<0><<<256, 512, 0, stream>>>((const void*)x, wih0b, whh0b, bih0, bhh0,
                                         hseq, (float*)nullptr);
  gru_kernel<1><<<256, 512, 0, stream>>>((const void*)hseq, wih1b, whh1b, bih1, bhh1,
                                         (u16*)nullptr, gbuf);

  norm_cvt<<<1024, 256, 0, stream>>>(gbuf, gbf, rng);
  cos_gemm<0><<<dim3(32, 32), 256, 0, stream>>>(gbf, gbf, rng, rng, simbuf,
                                                (u16*)nullptr, (float*)nullptr);

  hipMemsetAsync(ws + OFF_CONCEPT, 0, 2097152 + 32768, stream);  // concept+touched+colsum
  topk_scatter<<<4096, 256, 0, stream>>>(simbuf, gbuf, concept, touched);
  diag_valid<<<4096, 128, 0, stream>>>(simbuf, gbuf, touched, concept, valid);
  cf_kernel<<<2048, 256, 0, stream>>>(concept, W_hc, b_hc, valid, cf);
  norm_cvt<<<1024, 256, 0, stream>>>(cf, cfbf, rncf);

  cos_gemm<1><<<dim3(32, 32), 256, 0, stream>>>(gbf, cfbf, rng, rncf, (float*)nullptr,
                                                attnb, colsum);
  scale_cfT<<<2048, 256, 0, stream>>>(cf, colsum, cfTs);
  attn_cf<<<256, 256, 0, stream>>>(attnb, cfTs, hs_pre);

  head_kernel<<<256, 256, 0, stream>>>(hs_pre, gbuf, whsb, wforeb, wbackb, windib,
                                       b_hs, b_fore, b_back, b_indi, W_out, b_out,
                                       (float*)d_out);
}

// Round 3
// 543.782 us; speedup vs baseline: 1.5205x; 1.0374x over previous
//
#include <hip/hip_runtime.h>

// SGA_75531294867605 — GRU x2 -> cos-sim topK concept graph -> softmax attention head.
// R3: topk_scatter rewritten as histogram-select (R2's 20x full-row rescan was
//     VALU-bound, 139us): 2048-bin hist of |sim| float bits -> threshold bin ->
//     compact ~25 candidates -> 20 argmax rounds on ONE wave (no block barriers).

typedef float f32x4 __attribute__((ext_vector_type(4)));
typedef short s16x8 __attribute__((ext_vector_type(8)));
typedef unsigned short u16;
typedef unsigned long long u64;

#define DEVFN static __device__ __forceinline__

DEVFN u16 f2bf(float f) {
  union { float f; unsigned u; } v; v.f = f;
  return (u16)((v.u + 0x7FFFu + ((v.u >> 16) & 1u)) >> 16);  // RNE
}

DEVFN f32x4 mfma16(s16x8 a, s16x8 b, f32x4 c) {
  return __builtin_amdgcn_mfma_f32_16x16x32_bf16(a, b, c, 0, 0, 0);
}

DEVFN float sigmf(float x) { return __builtin_amdgcn_rcpf(1.f + __expf(-x)); }
DEVFN float tanhf_fast(float x) {
  float e = __expf(2.f * x);
  return 1.f - 2.f * __builtin_amdgcn_rcpf(e + 1.f);
}
DEVFN float lrelu(float v) { return v > 0.f ? v : 0.2f * v; }

// ---------------------------------------------------------------- all-weights fp32->bf16
__global__ void cvt_all(const float* __restrict__ w0, const float* __restrict__ w1,
                        const float* __restrict__ w2, const float* __restrict__ w3,
                        const float* __restrict__ w4, const float* __restrict__ w5,
                        const float* __restrict__ w6, const float* __restrict__ w7,
                        u16* __restrict__ dst) {
  int i = blockIdx.x * 256 + threadIdx.x;
  if (i >= 225280) return;
  float v;
  if      (i < 12288)  v = w0[i];
  else if (i < 61440)  v = w1[i - 12288];
  else if (i < 110592) v = w2[i - 61440];
  else if (i < 159744) v = w3[i - 110592];
  else if (i < 176128) v = w4[i - 159744];
  else if (i < 192512) v = w5[i - 176128];
  else if (i < 208896) v = w6[i - 192512];
  else                 v = w7[i - 208896];
  dst[i] = f2bf(v);
}

// ---------------------------------------------------------------- fused GRU layer
template<int LAYER>
__launch_bounds__(512, 1)
__global__ void gru_kernel(const void* __restrict__ xin,
                           const u16* __restrict__ Wih, const u16* __restrict__ Whh,
                           const float* __restrict__ bih, const float* __restrict__ bhh,
                           u16* __restrict__ hseq_out, float* __restrict__ g_out)
{
  constexpr int KIN = (LAYER == 0) ? 32 : 128;
  constexpr int NKK = KIN / 32;
  constexpr int XS  = (LAYER == 0) ? 40 : 136;
  const int tid  = threadIdx.x;
  const int w    = tid >> 6;
  const int l    = tid & 63;
  const int quad = l >> 4;
  const int l16  = l & 15;
  const int r0   = blockIdx.x * 16;
  const int c    = w * 16 + l16;

  __shared__ u16 sh_x[16 * XS];
  __shared__ u16 sh_hb[16 * 136];

  s16x8 Bih[3][NKK];
  s16x8 Bhh[3][4];
  float bi[3], bh[3];
#pragma unroll
  for (int g = 0; g < 3; ++g) {
    int j = g * 128 + c;
    bi[g] = bih[j];
    bh[g] = bhh[j];
#pragma unroll
    for (int kk = 0; kk < NKK; ++kk)
      Bih[g][kk] = *(const s16x8*)(Wih + j * KIN + kk * 32 + quad * 8);
#pragma unroll
    for (int kk = 0; kk < 4; ++kk)
      Bhh[g][kk] = *(const s16x8*)(Whh + j * 128 + kk * 32 + quad * 8);
  }
  float hreg[4] = {0.f, 0.f, 0.f, 0.f};
  for (int idx = tid; idx < 16 * 136; idx += 512) sh_hb[idx] = 0;

  for (int t = 0; t < 64; ++t) {
    if constexpr (LAYER == 0) {
      int r = tid >> 5, cc = tid & 31;
      float xv = ((const float*)xin)[(size_t)(r0 + r) * (64 * 32) + t * 32 + cc];
      sh_x[r * XS + cc] = f2bf(xv);
    } else {
      int r = tid >> 5, c4 = (tid & 31) * 4;
      *(ushort4*)(sh_x + r * XS + c4) =
        *(const ushort4*)((const u16*)xin + (size_t)(r0 + r) * (64 * 128) + t * 128 + c4);
    }
    __syncthreads();
    s16x8 ax[NKK], ah[4];
#pragma unroll
    for (int kk = 0; kk < NKK; ++kk)
      ax[kk] = *(const s16x8*)(sh_x + l16 * XS + kk * 32 + quad * 8);
#pragma unroll
    for (int kk = 0; kk < 4; ++kk)
      ah[kk] = *(const s16x8*)(sh_hb + l16 * 136 + kk * 32 + quad * 8);
    __syncthreads();

    f32x4 ai[3], ahh[3];
    const f32x4 zz4 = {0.f, 0.f, 0.f, 0.f};
#pragma unroll
    for (int g = 0; g < 3; ++g) { ai[g] = zz4; ahh[g] = zz4; }
#pragma unroll
    for (int g = 0; g < 3; ++g)
#pragma unroll
      for (int kk = 0; kk < NKK; ++kk) ai[g] = mfma16(ax[kk], Bih[g][kk], ai[g]);
#pragma unroll
    for (int g = 0; g < 3; ++g)
#pragma unroll
      for (int kk = 0; kk < 4; ++kk)  ahh[g] = mfma16(ah[kk], Bhh[g][kk], ahh[g]);

#pragma unroll
    for (int i = 0; i < 4; ++i) {
      int m = quad * 4 + i;
      float rr = sigmf(ai[0][i] + bi[0] + ahh[0][i] + bh[0]);
      float zg = sigmf(ai[1][i] + bi[1] + ahh[1][i] + bh[1]);
      float nn = tanhf_fast(ai[2][i] + bi[2] + rr * (ahh[2][i] + bh[2]));
      float hnew = (1.f - zg) * nn + zg * hreg[i];
      hreg[i] = hnew;
      u16 hb = f2bf(hnew);
      sh_hb[m * 136 + c] = hb;
      if constexpr (LAYER == 0) {
        hseq_out[(size_t)(r0 + m) * (64 * 128) + t * 128 + c] = hb;
      } else {
        if (t == 63) g_out[(size_t)(r0 + m) * 128 + c] = hnew;
      }
    }
  }
}

// ---------------------------------------------------------------- row norms + bf16
__global__ void norm_cvt(const float* __restrict__ src, u16* __restrict__ dst,
                         float* __restrict__ rn)
{
  const int tid = threadIdx.x;
  const int wv = tid >> 6, l = tid & 63;
  const int row = blockIdx.x * 4 + wv;
  float2 f2 = *(const float2*)(src + (size_t)row * 128 + l * 2);
  float s = f2.x * f2.x + f2.y * f2.y;
#pragma unroll
  for (int off = 32; off >= 1; off >>= 1) s += __shfl_xor(s, off);
  ushort2 p; p.x = f2bf(f2.x); p.y = f2bf(f2.y);
  *(ushort2*)(dst + (size_t)row * 128 + l * 2) = p;
  if (l == 0) rn[row] = (s == 0.f) ? 0.f : rsqrtf(s);
}

// ---------------------------------------------------------------- cos-sim GEMM
template<int MODE>
__launch_bounds__(256, 1)
__global__ void cos_gemm(const u16* __restrict__ A, const u16* __restrict__ B,
                         const float* __restrict__ rnA, const float* __restrict__ rnB,
                         float* __restrict__ C, u16* __restrict__ E,
                         float* __restrict__ colsum)
{
  __shared__ u16 shA[128 * 136];
  __shared__ u16 shB[128 * 136];
  const int tid = threadIdx.x;
  const int l = tid & 63, wv = tid >> 6;
  const int quad = l >> 4, l16 = l & 15;
  const int i0 = blockIdx.y * 128, j0 = blockIdx.x * 128;
  {
    int r = tid >> 1, half = tid & 1;
    const int4* sa = (const int4*)(A + (size_t)(i0 + r) * 128 + half * 64);
    int4* da = (int4*)(shA + r * 136 + half * 64);
    const int4* sb = (const int4*)(B + (size_t)(j0 + r) * 128 + half * 64);
    int4* db = (int4*)(shB + r * 136 + half * 64);
#pragma unroll
    for (int q = 0; q < 8; ++q) { da[q] = sa[q]; db[q] = sb[q]; }
  }
  __syncthreads();
  const int wm = wv >> 1, wn = wv & 1;
  f32x4 acc[4][4];
  const f32x4 zz4 = {0.f, 0.f, 0.f, 0.f};
#pragma unroll
  for (int a = 0; a < 4; ++a)
#pragma unroll
    for (int b = 0; b < 4; ++b) acc[a][b] = zz4;
#pragma unroll
  for (int kk = 0; kk < 4; ++kk) {
    s16x8 af[4], bfr[4];
#pragma unroll
    for (int mt = 0; mt < 4; ++mt)
      af[mt] = *(const s16x8*)(shA + (wm * 64 + mt * 16 + l16) * 136 + kk * 32 + quad * 8);
#pragma unroll
    for (int nt = 0; nt < 4; ++nt)
      bfr[nt] = *(const s16x8*)(shB + (wn * 64 + nt * 16 + l16) * 136 + kk * 32 + quad * 8);
#pragma unroll
    for (int mt = 0; mt < 4; ++mt)
#pragma unroll
      for (int nt = 0; nt < 4; ++nt) acc[mt][nt] = mfma16(af[mt], bfr[nt], acc[mt][nt]);
  }
  float ra[4][4];
#pragma unroll
  for (int mt = 0; mt < 4; ++mt)
#pragma unroll
    for (int i = 0; i < 4; ++i) ra[mt][i] = rnA[i0 + wm * 64 + mt * 16 + quad * 4 + i];
#pragma unroll
  for (int nt = 0; nt < 4; ++nt) {
    int col = j0 + wn * 64 + nt * 16 + l16;
    float rb = rnB[col];
    float psum = 0.f;
#pragma unroll
    for (int mt = 0; mt < 4; ++mt)
#pragma unroll
      for (int i = 0; i < 4; ++i) {
        int row = i0 + wm * 64 + mt * 16 + quad * 4 + i;
        float v = acc[mt][nt][i] * ra[mt][i] * rb;
        if constexpr (MODE == 0) {
          C[(size_t)row * 4096 + col] = v;
        } else {
          float e = __expf(v);
          E[(size_t)row * 4096 + col] = f2bf(e);
          psum += e;
        }
      }
    if constexpr (MODE == 1) {
      psum += __shfl_xor(psum, 16);
      psum += __shfl_xor(psum, 32);
      if (quad == 0) atomicAdd(colsum + col, psum);
    }
  }
}

// ---------------------------------------------------------------- topK via histogram select
// Keys = |sim| float bits (monotone). Hist 2048 bins (bits>>19) -> suffix scan
// finds bin b holding the 20th largest -> compact candidates (bin>=b) as packed
// u64 (key<<32 | 4095-idx, jax lower-index tie-break) -> 20 argmax rounds on
// wave 0 only (shfl butterfly, no block barriers). Exact for any input (cand
// holds up to all 4096). Diag participates with key 0 == ref's sim_off.
__launch_bounds__(256, 1)
__global__ void topk_scatter(const float* __restrict__ sim, const float* __restrict__ g,
                             float* __restrict__ concept, int* __restrict__ touched)
{
  __shared__ unsigned hist[2048];
  __shared__ u64 cand[4096];
  __shared__ float gs[128];
  __shared__ int selj[20];
  __shared__ float selv[20];
  __shared__ unsigned ws4[4];
  __shared__ int shb, shcnt;
  const int tid = threadIdx.x;
  const int row = blockIdx.x;
  const int l = tid & 63, wv = tid >> 6;

  for (int i = tid; i < 2048; i += 256) hist[i] = 0;
  if (tid == 0) shcnt = 0;
  if (tid < 128) gs[tid] = g[(size_t)row * 128 + tid];
  __syncthreads();

  unsigned key[16];
#pragma unroll
  for (int q = 0; q < 16; ++q) {
    int e = q * 256 + tid;
    float v = sim[(size_t)row * 4096 + e];
    unsigned kb = __float_as_uint(v) & 0x7FFFFFFFu;
    if (e == row) kb = 0u;                       // sim_off diag = 0
    key[q] = kb;
    unsigned bin = kb >> 19; if (bin > 2047u) bin = 2047u;
    atomicAdd(&hist[bin], 1u);
  }
  __syncthreads();

  // suffix counts: find largest bin b with count(bins >= b) >= 20
  unsigned s = 0;
#pragma unroll
  for (int j = 0; j < 8; ++j) s += hist[tid * 8 + j];
  unsigned r = s;
#pragma unroll
  for (int off = 1; off < 64; off <<= 1) {
    unsigned o = __shfl_down(r, off);
    if (l + off < 64) r += o;                    // r = sum over lanes >= l
  }
  if (l == 0) ws4[wv] = r;
  __syncthreads();
  unsigned upper = 0;
  for (int q = wv + 1; q < 4; ++q) upper += ws4[q];
  unsigned excl = upper + (r - s);               // count strictly above my 8 bins
  if (excl < 20u && excl + s >= 20u) {
    unsigned cum = excl;
    for (int j = 7; j >= 0; --j) {
      cum += hist[tid * 8 + j];
      if (cum >= 20u) { shb = tid * 8 + j; break; }
    }
  }
  __syncthreads();
  const unsigned b = (unsigned)shb;

  // compact candidates
#pragma unroll
  for (int q = 0; q < 16; ++q) {
    unsigned bin = key[q] >> 19; if (bin > 2047u) bin = 2047u;
    if (bin >= b) {
      int p = atomicAdd(&shcnt, 1);
      cand[p] = ((u64)key[q] << 32) | (u64)(4095 - (q * 256 + tid));
    }
  }
  __syncthreads();
  const int C = shcnt;

  if (wv == 0) {
    for (int it = 0; it < 20; ++it) {
      u64 best = 0ull; int bpos = -1;
      for (int p = l; p < C; p += 64) {
        u64 cv = cand[p];
        if (cv > best) { best = cv; bpos = p; }
      }
      u64 mine = best;
#pragma unroll
      for (int off = 1; off < 64; off <<= 1) {
        u64 o = __shfl_xor(best, off);
        if (o > best) best = o;
      }
      if (mine == best && bpos >= 0) cand[bpos] = 0ull;   // unique owner invalidates
      if (l == 0) selj[it] = 4095 - (int)(best & 0xFFFull);
    }
  }
  __syncthreads();
  if (tid < 20) {
    int idx = selj[tid];
    float sv = (idx == row) ? 0.f : sim[(size_t)row * 4096 + idx];
    selv[tid] = sv;
    if (sv != 0.f) atomicOr(touched + idx, 1);
  }
  __syncthreads();
  for (int idx = tid; idx < 20 * 128; idx += 256) {
    int it = idx >> 7, d = idx & 127;
    atomicAdd(concept + (size_t)selj[it] * 128 + d, selv[it] * gs[d]);
  }
}

// ---------------------------------------------------------------- diag add + valid
__global__ void diag_valid(const float* __restrict__ sim, const float* __restrict__ g,
                           const int* __restrict__ touched, float* __restrict__ concept,
                           float* __restrict__ valid)
{
  const int j = blockIdx.x, tid = threadIdx.x;
  const int l = tid & 63, wv = tid >> 6;
  __shared__ float ds[2];
  float cv = concept[(size_t)j * 128 + tid];
  if (touched[j]) cv += sim[(size_t)j * 4096 + j] * g[(size_t)j * 128 + tid];
  concept[(size_t)j * 128 + tid] = cv;
  float s = cv;
#pragma unroll
  for (int off = 32; off >= 1; off >>= 1) s += __shfl_down(s, off);
  if (l == 0) ds[wv] = s;
  __syncthreads();
  if (tid == 0) valid[j] = ((ds[0] + ds[1]) != 0.f) ? 1.f : 0.f;
}

// ---------------------------------------------------------------- cf = lrelu(concept@Whc.T+b)*valid
__global__ void cf_kernel(const float* __restrict__ concept, const float* __restrict__ Whc,
                          const float* __restrict__ bhc, const float* __restrict__ valid,
                          float* __restrict__ cf)
{
  int idx = blockIdx.x * 256 + threadIdx.x;
  int j = idx >> 7, o = idx & 127;
  const float4* cr = (const float4*)(concept + (size_t)j * 128);
  const float4* wr = (const float4*)(Whc + (size_t)o * 128);
  float s = bhc[o];
#pragma unroll 8
  for (int q = 0; q < 32; ++q) {
    float4 a = cr[q], b = wr[q];
    s += a.x * b.x + a.y * b.y + a.z * b.z + a.w * b.w;
  }
  cf[idx] = lrelu(s) * valid[j];
}

// ---------------------------------------------------------------- cfTs[n][c] = bf16(cf[c][n]/Z[c])
__global__ void scale_cfT(const float* __restrict__ cf, const float* __restrict__ colsum,
                          u16* __restrict__ cfTs)
{
  int idx = blockIdx.x * 256 + threadIdx.x;
  int n = idx >> 12, c = idx & 4095;
  float rz = __builtin_amdgcn_rcpf(colsum[c]);
  cfTs[idx] = f2bf(cf[(size_t)c * 128 + n] * rz);
}

// ---------------------------------------------------------------- hs_pre = E @ cfTs.T
__launch_bounds__(256, 1)
__global__ void attn_cf(const u16* __restrict__ attn, const u16* __restrict__ cfT,
                        float* __restrict__ hs_pre)
{
  __shared__ u16 shw[16 * 136];
  const int tid = threadIdx.x;
  const int l = tid & 63, wv = tid >> 6;
  const int quad = l >> 4, l16 = l & 15;
  const int r0 = blockIdx.x * 16;
  f32x4 acc[2];
  const f32x4 zz4 = {0.f, 0.f, 0.f, 0.f};
  acc[0] = zz4; acc[1] = zz4;
  for (int kc = 0; kc < 32; ++kc) {
    if (kc) __syncthreads();
    {
      int r = tid >> 4, seg = tid & 15;
      *(int4*)(shw + r * 136 + seg * 8) =
        *(const int4*)(attn + (size_t)(r0 + r) * 4096 + kc * 128 + seg * 8);
    }
    __syncthreads();
#pragma unroll
    for (int kk = 0; kk < 4; ++kk) {
      s16x8 a = *(const s16x8*)(shw + l16 * 136 + kk * 32 + quad * 8);
#pragma unroll
      for (int nt = 0; nt < 2; ++nt) {
        int n = wv * 32 + nt * 16 + l16;
        s16x8 b = *(const s16x8*)(cfT + (size_t)n * 4096 + kc * 128 + kk * 32 + quad * 8);
        acc[nt] = mfma16(a, b, acc[nt]);
      }
    }
  }
#pragma unroll
  for (int nt = 0; nt < 2; ++nt)
#pragma unroll
    for (int i = 0; i < 4; ++i) {
      int row = r0 + quad * 4 + i;
      int col = wv * 32 + nt * 16 + l16;
      hs_pre[(size_t)row * 128 + col] = acc[nt][i];
    }
}

// ---------------------------------------------------------------- head: MFMA chain
__launch_bounds__(256, 1)
__global__ void head_kernel(const float* __restrict__ hs_pre, const float* __restrict__ g,
                            const u16* __restrict__ whs, const u16* __restrict__ wfore,
                            const u16* __restrict__ wback, const u16* __restrict__ windi,
                            const float* __restrict__ b_hs, const float* __restrict__ b_fore,
                            const float* __restrict__ b_back, const float* __restrict__ b_indi,
                            const float* __restrict__ W_out, const float* __restrict__ b_out,
                            float* __restrict__ outp)
{
  __shared__ u16 bufin[16 * 136];
  __shared__ u16 bufB[16 * 136];
  __shared__ float bufF[16 * 132];
  __shared__ float shWout[128];
  const int tid = threadIdx.x;
  const int l = tid & 63, wv = tid >> 6;
  const int quad = l >> 4, l16 = l & 15;
  const int r0 = blockIdx.x * 16;
  const f32x4 zz4 = {0.f, 0.f, 0.f, 0.f};

  if (tid < 128) shWout[tid] = W_out[tid];
  for (int idx = tid; idx < 2048; idx += 256) {
    int j = idx >> 7, n = idx & 127;
    bufin[j * 136 + n] = f2bf(hs_pre[(size_t)(r0 + j) * 128 + n]);
  }
  __syncthreads();
  {
    s16x8 a[4];
#pragma unroll
    for (int kk = 0; kk < 4; ++kk)
      a[kk] = *(const s16x8*)(bufin + l16 * 136 + kk * 32 + quad * 8);
    f32x4 acc[2]; acc[0] = zz4; acc[1] = zz4;
#pragma unroll
    for (int nt = 0; nt < 2; ++nt) {
      int n = wv * 32 + nt * 16 + l16;
#pragma unroll
      for (int kk = 0; kk < 4; ++kk)
        acc[nt] = mfma16(a[kk], *(const s16x8*)(whs + n * 128 + kk * 32 + quad * 8), acc[nt]);
    }
#pragma unroll
    for (int nt = 0; nt < 2; ++nt) {
      int n = wv * 32 + nt * 16 + l16;
      float bb = b_hs[n];
#pragma unroll
      for (int i = 0; i < 4; ++i)
        bufB[(quad * 4 + i) * 136 + n] = f2bf(lrelu(acc[nt][i] + bb));
    }
  }
  __syncthreads();
  {
    s16x8 a[4];
#pragma unroll
    for (int kk = 0; kk < 4; ++kk)
      a[kk] = *(const s16x8*)(bufB + l16 * 136 + kk * 32 + quad * 8);
    f32x4 aF[2], aB[2]; aF[0] = zz4; aF[1] = zz4; aB[0] = zz4; aB[1] = zz4;
#pragma unroll
    for (int nt = 0; nt < 2; ++nt) {
      int n = wv * 32 + nt * 16 + l16;
#pragma unroll
      for (int kk = 0; kk < 4; ++kk) {
        aF[nt] = mfma16(a[kk], *(const s16x8*)(wfore + n * 128 + kk * 32 + quad * 8), aF[nt]);
        aB[nt] = mfma16(a[kk], *(const s16x8*)(wback + n * 128 + kk * 32 + quad * 8), aB[nt]);
      }
    }
#pragma unroll
    for (int nt = 0; nt < 2; ++nt) {
      int n = wv * 32 + nt * 16 + l16;
      float bf_ = b_fore[n], bb_ = b_back[n];
#pragma unroll
      for (int i = 0; i < 4; ++i) {
        int m = quad * 4 + i;
        bufF[m * 132 + n] = lrelu(aF[nt][i] + bf_);
        float back = lrelu(aB[nt][i] + bb_);
        float gv = g[(size_t)(r0 + m) * 128 + n];
        bufin[m * 136 + n] = f2bf(gv - back);
      }
    }
  }
  __syncthreads();
  {
    s16x8 a[4];
#pragma unroll
    for (int kk = 0; kk < 4; ++kk)
      a[kk] = *(const s16x8*)(bufin + l16 * 136 + kk * 32 + quad * 8);
    f32x4 acc[2]; acc[0] = zz4; acc[1] = zz4;
#pragma unroll
    for (int nt = 0; nt < 2; ++nt) {
      int n = wv * 32 + nt * 16 + l16;
#pragma unroll
      for (int kk = 0; kk < 4; ++kk)
        acc[nt] = mfma16(a[kk], *(const s16x8*)(windi + n * 128 + kk * 32 + quad * 8), acc[nt]);
    }
#pragma unroll
    for (int nt = 0; nt < 2; ++nt) {
      int n = wv * 32 + nt * 16 + l16;
      float bi_ = b_indi[n];
#pragma unroll
      for (int i = 0; i < 4; ++i)
        bufF[(quad * 4 + i) * 132 + n] += lrelu(acc[nt][i] + bi_);
    }
  }
  __syncthreads();
  if (tid < 16) {
    float s = b_out[0];
    const float* fr = bufF + tid * 132;
    for (int n = 0; n < 128; ++n) s += fr[n] * shWout[n];
    outp[r0 + tid] = s;
  }
}

// ---------------------------------------------------------------- workspace layout
static const size_t OFF_A       = 0;             // 67,108,864  hseq bf16 / sim fp32
static const size_t OFF_ATTN    = 67108864;      // 33,554,432  attn numerator bf16
static const size_t OFF_G       = 100663296;
static const size_t OFF_GBF     = 102760448;
static const size_t OFF_RNG     = 103809024;
static const size_t OFF_CONCEPT = 103825408;
static const size_t OFF_TOUCH   = 105922560;
static const size_t OFF_COLSUM  = 105938944;
static const size_t OFF_VALID   = 105955328;
static const size_t OFF_CF      = 105971712;
static const size_t OFF_CFBF    = 108068864;
static const size_t OFF_CFTS    = 109117440;
static const size_t OFF_RNCF    = 110166016;
static const size_t OFF_HSPRE   = 110182400;
static const size_t OFF_WB      = 112279552;

extern "C" void kernel_launch(void* const* d_in, const int* in_sizes, int n_in,
                              void* d_out, int out_size, void* d_ws, size_t ws_size,
                              hipStream_t stream)
{
  (void)in_sizes; (void)n_in; (void)out_size; (void)ws_size;
  const float* x      = (const float*)d_in[0];
  const float* Wih0   = (const float*)d_in[1];
  const float* Whh0   = (const float*)d_in[2];
  const float* bih0   = (const float*)d_in[3];
  const float* bhh0   = (const float*)d_in[4];
  const float* Wih1   = (const float*)d_in[5];
  const float* Whh1   = (const float*)d_in[6];
  const float* bih1   = (const float*)d_in[7];
  const float* bhh1   = (const float*)d_in[8];
  const float* W_hc   = (const float*)d_in[9];
  const float* b_hc   = (const float*)d_in[10];
  const float* W_hs   = (const float*)d_in[11];
  const float* b_hs   = (const float*)d_in[12];
  const float* W_fore = (const float*)d_in[13];
  const float* b_fore = (const float*)d_in[14];
  const float* W_back = (const float*)d_in[15];
  const float* b_back = (const float*)d_in[16];
  const float* W_indi = (const float*)d_in[17];
  const float* b_indi = (const float*)d_in[18];
  const float* W_out  = (const float*)d_in[19];
  const float* b_out  = (const float*)d_in[20];

  char* ws = (char*)d_ws;
  u16*   hseq    = (u16*)(ws + OFF_A);
  float* simbuf  = (float*)(ws + OFF_A);
  u16*   attnb   = (u16*)(ws + OFF_ATTN);
  float* gbuf    = (float*)(ws + OFF_G);
  u16*   gbf     = (u16*)(ws + OFF_GBF);
  float* rng     = (float*)(ws + OFF_RNG);
  float* concept = (float*)(ws + OFF_CONCEPT);
  int*   touched = (int*)(ws + OFF_TOUCH);
  float* colsum  = (float*)(ws + OFF_COLSUM);
  float* valid   = (float*)(ws + OFF_VALID);
  float* cf      = (float*)(ws + OFF_CF);
  u16*   cfbf    = (u16*)(ws + OFF_CFBF);
  u16*   cfTs    = (u16*)(ws + OFF_CFTS);
  float* rncf    = (float*)(ws + OFF_RNCF);
  float* hs_pre  = (float*)(ws + OFF_HSPRE);
  u16*   wsB     = (u16*)(ws + OFF_WB);
  u16 *wih0b = wsB, *whh0b = wsB + 12288, *wih1b = wsB + 61440, *whh1b = wsB + 110592;
  u16 *whsb = wsB + 159744, *wforeb = wsB + 176128, *wbackb = wsB + 192512, *windib = wsB + 208896;

  cvt_all<<<880, 256, 0, stream>>>(Wih0, Whh0, Wih1, Whh1, W_hs, W_fore, W_back, W_indi, wsB);

  gru_kernel<0><<<256, 512, 0, stream>>>((const void*)x, wih0b, whh0b, bih0, bhh0,
                                         hseq, (float*)nullptr);
  gru_kernel<1><<<256, 512, 0, stream>>>((const void*)hseq, wih1b, whh1b, bih1, bhh1,
                                         (u16*)nullptr, gbuf);

  norm_cvt<<<1024, 256, 0, stream>>>(gbuf, gbf, rng);
  cos_gemm<0><<<dim3(32, 32), 256, 0, stream>>>(gbf, gbf, rng, rng, simbuf,
                                                (u16*)nullptr, (float*)nullptr);

  hipMemsetAsync(ws + OFF_CONCEPT, 0, 2097152 + 32768, stream);
  topk_scatter<<<4096, 256, 0, stream>>>(simbuf, gbuf, concept, touched);
  diag_valid<<<4096, 128, 0, stream>>>(simbuf, gbuf, touched, concept, valid);
  cf_kernel<<<2048, 256, 0, stream>>>(concept, W_hc, b_hc, valid, cf);
  norm_cvt<<<1024, 256, 0, stream>>>(cf, cfbf, rncf);

  cos_gemm<1><<<dim3(32, 32), 256, 0, stream>>>(gbf, cfbf, rng, rncf, (float*)nullptr,
                                                attnb, colsum);
  scale_cfT<<<2048, 256, 0, stream>>>(cf, colsum, cfTs);
  attn_cf<<<256, 256, 0, stream>>>(attnb, cfTs, hs_pre);

  head_kernel<<<256, 256, 0, stream>>>(hs_pre, gbuf, whsb, wforeb, wbackb, windib,
                                       b_hs, b_fore, b_back, b_indi, W_out, b_out,
                                       (float*)d_out);
}

// Round 4
// 499.026 us; speedup vs baseline: 1.6568x; 1.0897x over previous
//
#include <hip/hip_runtime.h>

// SGA_75531294867605 — GRU x2 -> cos-sim topK concept graph -> softmax attention head.
// R4: de-atomized concept scatter (R3's 10.5M global atomicAdds -> CSR counting
//     sort, 82K atomics), select LDS 42->32KB (5 blocks/CU), and concept/diag/
//     valid/cf/norm fused into one gather kernel (3 launches deleted).

typedef float f32x4 __attribute__((ext_vector_type(4)));
typedef short s16x8 __attribute__((ext_vector_type(8)));
typedef unsigned short u16;
typedef unsigned long long u64;

#define DEVFN static __device__ __forceinline__

DEVFN u16 f2bf(float f) {
  union { float f; unsigned u; } v; v.f = f;
  return (u16)((v.u + 0x7FFFu + ((v.u >> 16) & 1u)) >> 16);  // RNE
}

DEVFN f32x4 mfma16(s16x8 a, s16x8 b, f32x4 c) {
  return __builtin_amdgcn_mfma_f32_16x16x32_bf16(a, b, c, 0, 0, 0);
}

DEVFN float sigmf(float x) { return __builtin_amdgcn_rcpf(1.f + __expf(-x)); }
DEVFN float tanhf_fast(float x) {
  float e = __expf(2.f * x);
  return 1.f - 2.f * __builtin_amdgcn_rcpf(e + 1.f);
}
DEVFN float lrelu(float v) { return v > 0.f ? v : 0.2f * v; }

// ---------------------------------------------------------------- all-weights fp32->bf16
__global__ void cvt_all(const float* __restrict__ w0, const float* __restrict__ w1,
                        const float* __restrict__ w2, const float* __restrict__ w3,
                        const float* __restrict__ w4, const float* __restrict__ w5,
                        const float* __restrict__ w6, const float* __restrict__ w7,
                        u16* __restrict__ dst) {
  int i = blockIdx.x * 256 + threadIdx.x;
  if (i >= 225280) return;
  float v;
  if      (i < 12288)  v = w0[i];
  else if (i < 61440)  v = w1[i - 12288];
  else if (i < 110592) v = w2[i - 61440];
  else if (i < 159744) v = w3[i - 110592];
  else if (i < 176128) v = w4[i - 159744];
  else if (i < 192512) v = w5[i - 176128];
  else if (i < 208896) v = w6[i - 192512];
  else                 v = w7[i - 208896];
  dst[i] = f2bf(v);
}

// ---------------------------------------------------------------- fused GRU layer
template<int LAYER>
__launch_bounds__(512, 1)
__global__ void gru_kernel(const void* __restrict__ xin,
                           const u16* __restrict__ Wih, const u16* __restrict__ Whh,
                           const float* __restrict__ bih, const float* __restrict__ bhh,
                           u16* __restrict__ hseq_out, float* __restrict__ g_out)
{
  constexpr int KIN = (LAYER == 0) ? 32 : 128;
  constexpr int NKK = KIN / 32;
  constexpr int XS  = (LAYER == 0) ? 40 : 136;
  const int tid  = threadIdx.x;
  const int w    = tid >> 6;
  const int l    = tid & 63;
  const int quad = l >> 4;
  const int l16  = l & 15;
  const int r0   = blockIdx.x * 16;
  const int c    = w * 16 + l16;

  __shared__ u16 sh_x[16 * XS];
  __shared__ u16 sh_hb[16 * 136];

  s16x8 Bih[3][NKK];
  s16x8 Bhh[3][4];
  float bi[3], bh[3];
#pragma unroll
  for (int g = 0; g < 3; ++g) {
    int j = g * 128 + c;
    bi[g] = bih[j];
    bh[g] = bhh[j];
#pragma unroll
    for (int kk = 0; kk < NKK; ++kk)
      Bih[g][kk] = *(const s16x8*)(Wih + j * KIN + kk * 32 + quad * 8);
#pragma unroll
    for (int kk = 0; kk < 4; ++kk)
      Bhh[g][kk] = *(const s16x8*)(Whh + j * 128 + kk * 32 + quad * 8);
  }
  float hreg[4] = {0.f, 0.f, 0.f, 0.f};
  for (int idx = tid; idx < 16 * 136; idx += 512) sh_hb[idx] = 0;

  for (int t = 0; t < 64; ++t) {
    if constexpr (LAYER == 0) {
      int r = tid >> 5, cc = tid & 31;
      float xv = ((const float*)xin)[(size_t)(r0 + r) * (64 * 32) + t * 32 + cc];
      sh_x[r * XS + cc] = f2bf(xv);
    } else {
      int r = tid >> 5, c4 = (tid & 31) * 4;
      *(ushort4*)(sh_x + r * XS + c4) =
        *(const ushort4*)((const u16*)xin + (size_t)(r0 + r) * (64 * 128) + t * 128 + c4);
    }
    __syncthreads();
    s16x8 ax[NKK], ah[4];
#pragma unroll
    for (int kk = 0; kk < NKK; ++kk)
      ax[kk] = *(const s16x8*)(sh_x + l16 * XS + kk * 32 + quad * 8);
#pragma unroll
    for (int kk = 0; kk < 4; ++kk)
      ah[kk] = *(const s16x8*)(sh_hb + l16 * 136 + kk * 32 + quad * 8);
    __syncthreads();

    f32x4 ai[3], ahh[3];
    const f32x4 zz4 = {0.f, 0.f, 0.f, 0.f};
#pragma unroll
    for (int g = 0; g < 3; ++g) { ai[g] = zz4; ahh[g] = zz4; }
#pragma unroll
    for (int g = 0; g < 3; ++g)
#pragma unroll
      for (int kk = 0; kk < NKK; ++kk) ai[g] = mfma16(ax[kk], Bih[g][kk], ai[g]);
#pragma unroll
    for (int g = 0; g < 3; ++g)
#pragma unroll
      for (int kk = 0; kk < 4; ++kk)  ahh[g] = mfma16(ah[kk], Bhh[g][kk], ahh[g]);

#pragma unroll
    for (int i = 0; i < 4; ++i) {
      int m = quad * 4 + i;
      float rr = sigmf(ai[0][i] + bi[0] + ahh[0][i] + bh[0]);
      float zg = sigmf(ai[1][i] + bi[1] + ahh[1][i] + bh[1]);
      float nn = tanhf_fast(ai[2][i] + bi[2] + rr * (ahh[2][i] + bh[2]));
      float hnew = (1.f - zg) * nn + zg * hreg[i];
      hreg[i] = hnew;
      u16 hb = f2bf(hnew);
      sh_hb[m * 136 + c] = hb;
      if constexpr (LAYER == 0) {
        hseq_out[(size_t)(r0 + m) * (64 * 128) + t * 128 + c] = hb;
      } else {
        if (t == 63) g_out[(size_t)(r0 + m) * 128 + c] = hnew;
      }
    }
  }
}

// ---------------------------------------------------------------- row norms + bf16
__global__ void norm_cvt(const float* __restrict__ src, u16* __restrict__ dst,
                         float* __restrict__ rn)
{
  const int tid = threadIdx.x;
  const int wv = tid >> 6, l = tid & 63;
  const int row = blockIdx.x * 4 + wv;
  float2 f2 = *(const float2*)(src + (size_t)row * 128 + l * 2);
  float s = f2.x * f2.x + f2.y * f2.y;
#pragma unroll
  for (int off = 32; off >= 1; off >>= 1) s += __shfl_xor(s, off);
  ushort2 p; p.x = f2bf(f2.x); p.y = f2bf(f2.y);
  *(ushort2*)(dst + (size_t)row * 128 + l * 2) = p;
  if (l == 0) rn[row] = (s == 0.f) ? 0.f : rsqrtf(s);
}

// ---------------------------------------------------------------- cos-sim GEMM
template<int MODE>
__launch_bounds__(256, 1)
__global__ void cos_gemm(const u16* __restrict__ A, const u16* __restrict__ B,
                         const float* __restrict__ rnA, const float* __restrict__ rnB,
                         float* __restrict__ C, u16* __restrict__ E,
                         float* __restrict__ colsum)
{
  __shared__ u16 shA[128 * 136];
  __shared__ u16 shB[128 * 136];
  const int tid = threadIdx.x;
  const int l = tid & 63, wv = tid >> 6;
  const int quad = l >> 4, l16 = l & 15;
  const int i0 = blockIdx.y * 128, j0 = blockIdx.x * 128;
  {
    int r = tid >> 1, half = tid & 1;
    const int4* sa = (const int4*)(A + (size_t)(i0 + r) * 128 + half * 64);
    int4* da = (int4*)(shA + r * 136 + half * 64);
    const int4* sb = (const int4*)(B + (size_t)(j0 + r) * 128 + half * 64);
    int4* db = (int4*)(shB + r * 136 + half * 64);
#pragma unroll
    for (int q = 0; q < 8; ++q) { da[q] = sa[q]; db[q] = sb[q]; }
  }
  __syncthreads();
  const int wm = wv >> 1, wn = wv & 1;
  f32x4 acc[4][4];
  const f32x4 zz4 = {0.f, 0.f, 0.f, 0.f};
#pragma unroll
  for (int a = 0; a < 4; ++a)
#pragma unroll
    for (int b = 0; b < 4; ++b) acc[a][b] = zz4;
#pragma unroll
  for (int kk = 0; kk < 4; ++kk) {
    s16x8 af[4], bfr[4];
#pragma unroll
    for (int mt = 0; mt < 4; ++mt)
      af[mt] = *(const s16x8*)(shA + (wm * 64 + mt * 16 + l16) * 136 + kk * 32 + quad * 8);
#pragma unroll
    for (int nt = 0; nt < 4; ++nt)
      bfr[nt] = *(const s16x8*)(shB + (wn * 64 + nt * 16 + l16) * 136 + kk * 32 + quad * 8);
#pragma unroll
    for (int mt = 0; mt < 4; ++mt)
#pragma unroll
      for (int nt = 0; nt < 4; ++nt) acc[mt][nt] = mfma16(af[mt], bfr[nt], acc[mt][nt]);
  }
  float ra[4][4];
#pragma unroll
  for (int mt = 0; mt < 4; ++mt)
#pragma unroll
    for (int i = 0; i < 4; ++i) ra[mt][i] = rnA[i0 + wm * 64 + mt * 16 + quad * 4 + i];
#pragma unroll
  for (int nt = 0; nt < 4; ++nt) {
    int col = j0 + wn * 64 + nt * 16 + l16;
    float rb = rnB[col];
    float psum = 0.f;
#pragma unroll
    for (int mt = 0; mt < 4; ++mt)
#pragma unroll
      for (int i = 0; i < 4; ++i) {
        int row = i0 + wm * 64 + mt * 16 + quad * 4 + i;
        float v = acc[mt][nt][i] * ra[mt][i] * rb;
        if constexpr (MODE == 0) {
          C[(size_t)row * 4096 + col] = v;
        } else {
          float e = __expf(v);
          E[(size_t)row * 4096 + col] = f2bf(e);
          psum += e;
        }
      }
    if constexpr (MODE == 1) {
      psum += __shfl_xor(psum, 16);
      psum += __shfl_xor(psum, 32);
      if (quad == 0) atomicAdd(colsum + col, psum);
    }
  }
}

// ---------------------------------------------------------------- topK select (no scatter)
// Hist 2048 bins of |sim| bits -> threshold bin -> compact candidates (packed
// key|4095-idx, lower-index tie-break) -> 20 argmax rounds on wave 0. Writes
// selj/selv per row, increments cnt[j] (20 atomics/row), sets touched.
__launch_bounds__(256, 1)
__global__ void topk_select(const float* __restrict__ sim,
                            int* __restrict__ gselj, float* __restrict__ gselv,
                            int* __restrict__ cnt, int* __restrict__ touched)
{
  __shared__ unsigned hist[2048];
  __shared__ u64 cand[3072];
  __shared__ int selj[20];
  __shared__ unsigned ws4[4];
  __shared__ int shb, shcnt;
  const int tid = threadIdx.x;
  const int row = blockIdx.x;
  const int l = tid & 63, wv = tid >> 6;

  for (int i = tid; i < 2048; i += 256) hist[i] = 0;
  if (tid == 0) shcnt = 0;
  __syncthreads();

  unsigned key[4][4];
#pragma unroll
  for (int q = 0; q < 4; ++q) {
    int e0 = (q * 256 + tid) * 4;
    float4 v = *(const float4*)(sim + (size_t)row * 4096 + e0);
    key[q][0] = (e0 + 0 == row) ? 0u : (__float_as_uint(v.x) & 0x7FFFFFFFu);
    key[q][1] = (e0 + 1 == row) ? 0u : (__float_as_uint(v.y) & 0x7FFFFFFFu);
    key[q][2] = (e0 + 2 == row) ? 0u : (__float_as_uint(v.z) & 0x7FFFFFFFu);
    key[q][3] = (e0 + 3 == row) ? 0u : (__float_as_uint(v.w) & 0x7FFFFFFFu);
#pragma unroll
    for (int c = 0; c < 4; ++c) {
      unsigned bin = key[q][c] >> 19; if (bin > 2047u) bin = 2047u;
      atomicAdd(&hist[bin], 1u);
    }
  }
  __syncthreads();

  unsigned s = 0;
#pragma unroll
  for (int j = 0; j < 8; ++j) s += hist[tid * 8 + j];
  unsigned r = s;
#pragma unroll
  for (int off = 1; off < 64; off <<= 1) {
    unsigned o = __shfl_down(r, off);
    if (l + off < 64) r += o;
  }
  if (l == 0) ws4[wv] = r;
  __syncthreads();
  unsigned upper = 0;
  for (int q = wv + 1; q < 4; ++q) upper += ws4[q];
  unsigned excl = upper + (r - s);
  if (excl < 20u && excl + s >= 20u) {
    unsigned cum = excl;
    for (int j = 7; j >= 0; --j) {
      cum += hist[tid * 8 + j];
      if (cum >= 20u) { shb = tid * 8 + j; break; }
    }
  }
  __syncthreads();
  const unsigned b = (unsigned)shb;

#pragma unroll
  for (int q = 0; q < 4; ++q) {
    int e0 = (q * 256 + tid) * 4;
#pragma unroll
    for (int c = 0; c < 4; ++c) {
      unsigned bin = key[q][c] >> 19; if (bin > 2047u) bin = 2047u;
      if (bin >= b) {
        int p = atomicAdd(&shcnt, 1);
        if (p < 3072) cand[p] = ((u64)key[q][c] << 32) | (u64)(4095 - (e0 + c));
      }
    }
  }
  __syncthreads();
  const int C = (shcnt < 3072) ? shcnt : 3072;

  if (wv == 0) {
    for (int it = 0; it < 20; ++it) {
      u64 best = 0ull; int bpos = -1;
      for (int p = l; p < C; p += 64) {
        u64 cv = cand[p];
        if (cv > best) { best = cv; bpos = p; }
      }
      u64 mine = best;
#pragma unroll
      for (int off = 1; off < 64; off <<= 1) {
        u64 o = __shfl_xor(best, off);
        if (o > best) best = o;
      }
      if (mine == best && bpos >= 0 && best != 0ull) cand[bpos] = 0ull;
      if (l == 0) selj[it] = 4095 - (int)(best & 0xFFFull);
    }
  }
  __syncthreads();
  if (tid < 20) {
    int idx = selj[tid];
    float sv = (idx == row) ? 0.f : sim[(size_t)row * 4096 + idx];
    gselj[row * 20 + tid] = idx;
    gselv[row * 20 + tid] = sv;
    atomicAdd(&cnt[idx], 1);
    if (sv != 0.f) atomicOr(touched + idx, 1);
  }
}

// ---------------------------------------------------------------- exclusive scan of cnt[4096]
__launch_bounds__(1024, 1)
__global__ void scan4096(const int* __restrict__ cnt, int* __restrict__ offs,
                         int* __restrict__ cur)
{
  __shared__ int wsum[16];
  const int t = threadIdx.x, l = t & 63, wv = t >> 6;
  int4 c = ((const int4*)cnt)[t];
  int s = c.x + c.y + c.z + c.w;
  int ps = s;
#pragma unroll
  for (int off = 1; off < 64; off <<= 1) {
    int o = __shfl_up(ps, off);
    if (l >= off) ps += o;
  }
  if (l == 63) wsum[wv] = ps;
  __syncthreads();
  if (t == 0) {
    int a = 0;
#pragma unroll
    for (int q = 0; q < 16; ++q) { int x = wsum[q]; wsum[q] = a; a += x; }
  }
  __syncthreads();
  int base = wsum[wv] + (ps - s);
  int4 o4;
  o4.x = base; o4.y = o4.x + c.x; o4.z = o4.y + c.y; o4.w = o4.z + c.z;
  ((int4*)offs)[t] = o4;
  ((int4*)cur)[t] = o4;
}

// ---------------------------------------------------------------- CSR entry scatter
__global__ void scatter_entries(const int* __restrict__ gselj, const float* __restrict__ gselv,
                                int* __restrict__ cur, int* __restrict__ eid,
                                float* __restrict__ ev)
{
  unsigned idx = blockIdx.x * 256 + threadIdx.x;   // 81920 total
  unsigned row = idx / 20u;
  int j = gselj[idx]; float v = gselv[idx];
  int pos = atomicAdd(&cur[j], 1);
  eid[pos] = (int)row; ev[pos] = v;
}

// ---------------------------------------------------------------- concept gather + cf fused
// Block per column j: concept_j = sum_entries v*g[i] (+ diag if touched), valid
// from row sum, cf = lrelu(concept@Whc.T + b)*valid, bf16 cvt + row norm. No
// atomics; concept never materialized in HBM.
__launch_bounds__(128, 1)
__global__ void concept_cf(const int* __restrict__ offs, const int* __restrict__ cnt,
                           const int* __restrict__ eid, const float* __restrict__ ev,
                           const float* __restrict__ g, const float* __restrict__ sim,
                           const int* __restrict__ touched,
                           const float* __restrict__ Whc, const float* __restrict__ bhc,
                           float* __restrict__ cf, u16* __restrict__ cfbf,
                           float* __restrict__ rncf)
{
  __shared__ float shc[128];
  __shared__ float red2[2];
  const int j = blockIdx.x, d = threadIdx.x;
  const int l = d & 63, wv = d >> 6;
  const int off = offs[j], n = cnt[j];
  float acc = 0.f;
  for (int p = 0; p < n; ++p) {
    int i = eid[off + p]; float v = ev[off + p];
    acc += v * g[(size_t)i * 128 + d];
  }
  if (touched[j]) acc += sim[(size_t)j * 4097] * g[(size_t)j * 128 + d];
  float s = acc;
#pragma unroll
  for (int o = 32; o >= 1; o >>= 1) s += __shfl_xor(s, o);
  if (l == 0) red2[wv] = s;
  shc[d] = acc;
  __syncthreads();
  float valid = ((red2[0] + red2[1]) != 0.f) ? 1.f : 0.f;
  float o = bhc[d];
  const float4* wr = (const float4*)(Whc + (size_t)d * 128);
#pragma unroll 8
  for (int q = 0; q < 32; ++q) {
    float4 w4 = wr[q];
    float4 c4 = *((const float4*)shc + q);
    o += c4.x * w4.x + c4.y * w4.y + c4.z * w4.z + c4.w * w4.w;
  }
  float cfv = lrelu(o) * valid;
  cf[(size_t)j * 128 + d] = cfv;
  cfbf[(size_t)j * 128 + d] = f2bf(cfv);
  __syncthreads();                     // red2 reuse
  float nn = cfv * cfv;
#pragma unroll
  for (int of = 32; of >= 1; of >>= 1) nn += __shfl_xor(nn, of);
  if (l == 0) red2[wv] = nn;
  __syncthreads();
  if (d == 0) {
    float q2 = red2[0] + red2[1];
    rncf[j] = (q2 == 0.f) ? 0.f : rsqrtf(q2);
  }
}

// ---------------------------------------------------------------- cfTs[n][c] = bf16(cf[c][n]/Z[c])
__global__ void scale_cfT(const float* __restrict__ cf, const float* __restrict__ colsum,
                          u16* __restrict__ cfTs)
{
  int idx = blockIdx.x * 256 + threadIdx.x;
  int n = idx >> 12, c = idx & 4095;
  float rz = __builtin_amdgcn_rcpf(colsum[c]);
  cfTs[idx] = f2bf(cf[(size_t)c * 128 + n] * rz);
}

// ---------------------------------------------------------------- hs_pre = E @ cfTs.T
__launch_bounds__(256, 1)
__global__ void attn_cf(const u16* __restrict__ attn, const u16* __restrict__ cfT,
                        float* __restrict__ hs_pre)
{
  __shared__ u16 shw[16 * 136];
  const int tid = threadIdx.x;
  const int l = tid & 63, wv = tid >> 6;
  const int quad = l >> 4, l16 = l & 15;
  const int r0 = blockIdx.x * 16;
  f32x4 acc[2];
  const f32x4 zz4 = {0.f, 0.f, 0.f, 0.f};
  acc[0] = zz4; acc[1] = zz4;
  for (int kc = 0; kc < 32; ++kc) {
    if (kc) __syncthreads();
    {
      int r = tid >> 4, seg = tid & 15;
      *(int4*)(shw + r * 136 + seg * 8) =
        *(const int4*)(attn + (size_t)(r0 + r) * 4096 + kc * 128 + seg * 8);
    }
    __syncthreads();
#pragma unroll
    for (int kk = 0; kk < 4; ++kk) {
      s16x8 a = *(const s16x8*)(shw + l16 * 136 + kk * 32 + quad * 8);
#pragma unroll
      for (int nt = 0; nt < 2; ++nt) {
        int n = wv * 32 + nt * 16 + l16;
        s16x8 b = *(const s16x8*)(cfT + (size_t)n * 4096 + kc * 128 + kk * 32 + quad * 8);
        acc[nt] = mfma16(a, b, acc[nt]);
      }
    }
  }
#pragma unroll
  for (int nt = 0; nt < 2; ++nt)
#pragma unroll
    for (int i = 0; i < 4; ++i) {
      int row = r0 + quad * 4 + i;
      int col = wv * 32 + nt * 16 + l16;
      hs_pre[(size_t)row * 128 + col] = acc[nt][i];
    }
}

// ---------------------------------------------------------------- head: MFMA chain
__launch_bounds__(256, 1)
__global__ void head_kernel(const float* __restrict__ hs_pre, const float* __restrict__ g,
                            const u16* __restrict__ whs, const u16* __restrict__ wfore,
                            const u16* __restrict__ wback, const u16* __restrict__ windi,
                            const float* __restrict__ b_hs, const float* __restrict__ b_fore,
                            const float* __restrict__ b_back, const float* __restrict__ b_indi,
                            const float* __restrict__ W_out, const float* __restrict__ b_out,
                            float* __restrict__ outp)
{
  __shared__ u16 bufin[16 * 136];
  __shared__ u16 bufB[16 * 136];
  __shared__ float bufF[16 * 132];
  __shared__ float shWout[128];
  const int tid = threadIdx.x;
  const int l = tid & 63, wv = tid >> 6;
  const int quad = l >> 4, l16 = l & 15;
  const int r0 = blockIdx.x * 16;
  const f32x4 zz4 = {0.f, 0.f, 0.f, 0.f};

  if (tid < 128) shWout[tid] = W_out[tid];
  for (int idx = tid; idx < 2048; idx += 256) {
    int j = idx >> 7, n = idx & 127;
    bufin[j * 136 + n] = f2bf(hs_pre[(size_t)(r0 + j) * 128 + n]);
  }
  __syncthreads();
  {
    s16x8 a[4];
#pragma unroll
    for (int kk = 0; kk < 4; ++kk)
      a[kk] = *(const s16x8*)(bufin + l16 * 136 + kk * 32 + quad * 8);
    f32x4 acc[2]; acc[0] = zz4; acc[1] = zz4;
#pragma unroll
    for (int nt = 0; nt < 2; ++nt) {
      int n = wv * 32 + nt * 16 + l16;
#pragma unroll
      for (int kk = 0; kk < 4; ++kk)
        acc[nt] = mfma16(a[kk], *(const s16x8*)(whs + n * 128 + kk * 32 + quad * 8), acc[nt]);
    }
#pragma unroll
    for (int nt = 0; nt < 2; ++nt) {
      int n = wv * 32 + nt * 16 + l16;
      float bb = b_hs[n];
#pragma unroll
      for (int i = 0; i < 4; ++i)
        bufB[(quad * 4 + i) * 136 + n] = f2bf(lrelu(acc[nt][i] + bb));
    }
  }
  __syncthreads();
  {
    s16x8 a[4];
#pragma unroll
    for (int kk = 0; kk < 4; ++kk)
      a[kk] = *(const s16x8*)(bufB + l16 * 136 + kk * 32 + quad * 8);
    f32x4 aF[2], aB[2]; aF[0] = zz4; aF[1] = zz4; aB[0] = zz4; aB[1] = zz4;
#pragma unroll
    for (int nt = 0; nt < 2; ++nt) {
      int n = wv * 32 + nt * 16 + l16;
#pragma unroll
      for (int kk = 0; kk < 4; ++kk) {
        aF[nt] = mfma16(a[kk], *(const s16x8*)(wfore + n * 128 + kk * 32 + quad * 8), aF[nt]);
        aB[nt] = mfma16(a[kk], *(const s16x8*)(wback + n * 128 + kk * 32 + quad * 8), aB[nt]);
      }
    }
#pragma unroll
    for (int nt = 0; nt < 2; ++nt) {
      int n = wv * 32 + nt * 16 + l16;
      float bf_ = b_fore[n], bb_ = b_back[n];
#pragma unroll
      for (int i = 0; i < 4; ++i) {
        int m = quad * 4 + i;
        bufF[m * 132 + n] = lrelu(aF[nt][i] + bf_);
        float back = lrelu(aB[nt][i] + bb_);
        float gv = g[(size_t)(r0 + m) * 128 + n];
        bufin[m * 136 + n] = f2bf(gv - back);
      }
    }
  }
  __syncthreads();
  {
    s16x8 a[4];
#pragma unroll
    for (int kk = 0; kk < 4; ++kk)
      a[kk] = *(const s16x8*)(bufin + l16 * 136 + kk * 32 + quad * 8);
    f32x4 acc[2]; acc[0] = zz4; acc[1] = zz4;
#pragma unroll
    for (int nt = 0; nt < 2; ++nt) {
      int n = wv * 32 + nt * 16 + l16;
#pragma unroll
      for (int kk = 0; kk < 4; ++kk)
        acc[nt] = mfma16(a[kk], *(const s16x8*)(windi + n * 128 + kk * 32 + quad * 8), acc[nt]);
    }
#pragma unroll
    for (int nt = 0; nt < 2; ++nt) {
      int n = wv * 32 + nt * 16 + l16;
      float bi_ = b_indi[n];
#pragma unroll
      for (int i = 0; i < 4; ++i)
        bufF[(quad * 4 + i) * 132 + n] += lrelu(acc[nt][i] + bi_);
    }
  }
  __syncthreads();
  if (tid < 16) {
    float s = b_out[0];
    const float* fr = bufF + tid * 132;
    for (int n = 0; n < 128; ++n) s += fr[n] * shWout[n];
    outp[r0 + tid] = s;
  }
}

// ---------------------------------------------------------------- workspace layout
static const size_t OFF_A       = 0;             // 67,108,864  hseq bf16 / sim fp32
static const size_t OFF_ATTN    = 67108864;      // 33,554,432  attn numerator bf16
static const size_t OFF_G       = 100663296;     //  2,097,152
static const size_t OFF_GBF     = 102760448;     //  1,048,576
static const size_t OFF_RNG     = 103809024;     //     16,384
static const size_t OFF_SELJ    = 103825408;     //    327,680
static const size_t OFF_SELV    = 104153088;     //    327,680
static const size_t OFF_EID     = 104480768;     //    327,680
static const size_t OFF_EV      = 104808448;     //    327,680
static const size_t OFF_CNT     = 105136128;     //     16,384  ┐
static const size_t OFF_TOUCH   = 105152512;     //     16,384  │ one 48KB memset
static const size_t OFF_COLSUM  = 105168896;     //     16,384  ┘
static const size_t OFF_OFFS    = 105185280;     //     16,384
static const size_t OFF_CUR     = 105201664;     //     16,384
static const size_t OFF_CF      = 105218048;     //  2,097,152
static const size_t OFF_CFBF    = 107315200;     //  1,048,576
static const size_t OFF_CFTS    = 108363776;     //  1,048,576
static const size_t OFF_RNCF    = 109412352;     //     16,384
static const size_t OFF_HSPRE   = 109428736;     //  2,097,152
static const size_t OFF_WB      = 111525888;     //    450,560  -> end 111,976,448

extern "C" void kernel_launch(void* const* d_in, const int* in_sizes, int n_in,
                              void* d_out, int out_size, void* d_ws, size_t ws_size,
                              hipStream_t stream)
{
  (void)in_sizes; (void)n_in; (void)out_size; (void)ws_size;
  const float* x      = (const float*)d_in[0];
  const float* Wih0   = (const float*)d_in[1];
  const float* Whh0   = (const float*)d_in[2];
  const float* bih0   = (const float*)d_in[3];
  const float* bhh0   = (const float*)d_in[4];
  const float* Wih1   = (const float*)d_in[5];
  const float* Whh1   = (const float*)d_in[6];
  const float* bih1   = (const float*)d_in[7];
  const float* bhh1   = (const float*)d_in[8];
  const float* W_hc   = (const float*)d_in[9];
  const float* b_hc   = (const float*)d_in[10];
  const float* W_hs   = (const float*)d_in[11];
  const float* b_hs   = (const float*)d_in[12];
  const float* W_fore = (const float*)d_in[13];
  const float* b_fore = (const float*)d_in[14];
  const float* W_back = (const float*)d_in[15];
  const float* b_back = (const float*)d_in[16];
  const float* W_indi = (const float*)d_in[17];
  const float* b_indi = (const float*)d_in[18];
  const float* W_out  = (const float*)d_in[19];
  const float* b_out  = (const float*)d_in[20];

  char* ws = (char*)d_ws;
  u16*   hseq    = (u16*)(ws + OFF_A);
  float* simbuf  = (float*)(ws + OFF_A);
  u16*   attnb   = (u16*)(ws + OFF_ATTN);
  float* gbuf    = (float*)(ws + OFF_G);
  u16*   gbf     = (u16*)(ws + OFF_GBF);
  float* rng     = (float*)(ws + OFF_RNG);
  int*   gselj   = (int*)(ws + OFF_SELJ);
  float* gselv   = (float*)(ws + OFF_SELV);
  int*   eid     = (int*)(ws + OFF_EID);
  float* ev      = (float*)(ws + OFF_EV);
  int*   cntb    = (int*)(ws + OFF_CNT);
  int*   touched = (int*)(ws + OFF_TOUCH);
  float* colsum  = (float*)(ws + OFF_COLSUM);
  int*   offsb   = (int*)(ws + OFF_OFFS);
  int*   curb    = (int*)(ws + OFF_CUR);
  float* cf      = (float*)(ws + OFF_CF);
  u16*   cfbf    = (u16*)(ws + OFF_CFBF);
  u16*   cfTs    = (u16*)(ws + OFF_CFTS);
  float* rncf    = (float*)(ws + OFF_RNCF);
  float* hs_pre  = (float*)(ws + OFF_HSPRE);
  u16*   wsB     = (u16*)(ws + OFF_WB);
  u16 *wih0b = wsB, *whh0b = wsB + 12288, *wih1b = wsB + 61440, *whh1b = wsB + 110592;
  u16 *whsb = wsB + 159744, *wforeb = wsB + 176128, *wbackb = wsB + 192512, *windib = wsB + 208896;

  cvt_all<<<880, 256, 0, stream>>>(Wih0, Whh0, Wih1, Whh1, W_hs, W_fore, W_back, W_indi, wsB);

  gru_kernel<0><<<256, 512, 0, stream>>>((const void*)x, wih0b, whh0b, bih0, bhh0,
                                         hseq, (float*)nullptr);
  gru_kernel<1><<<256, 512, 0, stream>>>((const void*)hseq, wih1b, whh1b, bih1, bhh1,
                                         (u16*)nullptr, gbuf);

  norm_cvt<<<1024, 256, 0, stream>>>(gbuf, gbf, rng);
  cos_gemm<0><<<dim3(32, 32), 256, 0, stream>>>(gbf, gbf, rng, rng, simbuf,
                                                (u16*)nullptr, (float*)nullptr);

  hipMemsetAsync(ws + OFF_CNT, 0, 49152, stream);   // cnt + touched + colsum
  topk_select<<<4096, 256, 0, stream>>>(simbuf, gselj, gselv, cntb, touched);
  scan4096<<<1, 1024, 0, stream>>>(cntb, offsb, curb);
  scatter_entries<<<320, 256, 0, stream>>>(gselj, gselv, curb, eid, ev);
  concept_cf<<<4096, 128, 0, stream>>>(offsb, cntb, eid, ev, gbuf, simbuf, touched,
                                       W_hc, b_hc, cf, cfbf, rncf);

  cos_gemm<1><<<dim3(32, 32), 256, 0, stream>>>(gbf, cfbf, rng, rncf, (float*)nullptr,
                                                attnb, colsum);
  scale_cfT<<<2048, 256, 0, stream>>>(cf, colsum, cfTs);
  attn_cf<<<256, 256, 0, stream>>>(attnb, cfTs, hs_pre);

  head_kernel<<<256, 256, 0, stream>>>(hs_pre, gbuf, whsb, wforeb, wbackb, windib,
                                       b_hs, b_fore, b_back, b_indi, W_out, b_out,
                                       (float*)d_out);
}

// Round 5
// 444.521 us; speedup vs baseline: 1.8600x; 1.1226x over previous
//
#include <hip/hip_runtime.h>

// SGA_75531294867605 — GRU x2 -> cos-sim topK concept graph -> softmax attention head.
// R5: both GRU layers fused in ONE kernel (R4: 2x~100us, serialization-bound at
//     3750 cyc/step). h0 passes L0->L1 through double-buffered LDS (hseq 128MB
//     HBM round-trip deleted), x prefetched into regs, 2 barriers/step total.

typedef float f32x4 __attribute__((ext_vector_type(4)));
typedef short s16x8 __attribute__((ext_vector_type(8)));
typedef unsigned short u16;
typedef unsigned long long u64;

#define DEVFN static __device__ __forceinline__

DEVFN u16 f2bf(float f) {
  union { float f; unsigned u; } v; v.f = f;
  return (u16)((v.u + 0x7FFFu + ((v.u >> 16) & 1u)) >> 16);  // RNE
}

DEVFN f32x4 mfma16(s16x8 a, s16x8 b, f32x4 c) {
  return __builtin_amdgcn_mfma_f32_16x16x32_bf16(a, b, c, 0, 0, 0);
}

DEVFN float sigmf(float x) { return __builtin_amdgcn_rcpf(1.f + __expf(-x)); }
DEVFN float tanhf_fast(float x) {
  float e = __expf(2.f * x);
  return 1.f - 2.f * __builtin_amdgcn_rcpf(e + 1.f);
}
DEVFN float lrelu(float v) { return v > 0.f ? v : 0.2f * v; }

// ---------------------------------------------------------------- all-weights fp32->bf16
__global__ void cvt_all(const float* __restrict__ w0, const float* __restrict__ w1,
                        const float* __restrict__ w2, const float* __restrict__ w3,
                        const float* __restrict__ w4, const float* __restrict__ w5,
                        const float* __restrict__ w6, const float* __restrict__ w7,
                        u16* __restrict__ dst) {
  int i = blockIdx.x * 256 + threadIdx.x;
  if (i >= 225280) return;
  float v;
  if      (i < 12288)  v = w0[i];
  else if (i < 61440)  v = w1[i - 12288];
  else if (i < 110592) v = w2[i - 61440];
  else if (i < 159744) v = w3[i - 110592];
  else if (i < 176128) v = w4[i - 159744];
  else if (i < 192512) v = w5[i - 176128];
  else if (i < 208896) v = w6[i - 192512];
  else                 v = w7[i - 208896];
  dst[i] = f2bf(v);
}

// ---------------------------------------------------------------- fused 2-layer GRU
// Block: 512 thr (8 waves) x 16 rows x all 64 steps, BOTH layers. Wave w owns
// H-cols [16w,16w+16) for every gate of both layers; all recurrent weights are
// persistent MFMA B-frags (156 VGPRs). h0 crosses L0->L1 via LDS dbuf (bf16 —
// bit-identical to the old hseq round-trip). x(t+1) prefetched into regs.
__launch_bounds__(512, 2)
__global__ void gru_fused(const float* __restrict__ x,
                          const u16* __restrict__ Wih0, const u16* __restrict__ Whh0,
                          const float* __restrict__ bih0, const float* __restrict__ bhh0,
                          const u16* __restrict__ Wih1, const u16* __restrict__ Whh1,
                          const float* __restrict__ bih1, const float* __restrict__ bhh1,
                          float* __restrict__ g_out)
{
  const int tid  = threadIdx.x;
  const int w    = tid >> 6;
  const int l    = tid & 63;
  const int quad = l >> 4;
  const int l16  = l & 15;
  const int r0   = blockIdx.x * 16;
  const int c    = w * 16 + l16;

  __shared__ u16 sh_x[16 * 40];
  __shared__ u16 sh_h0[2][16 * 136];
  __shared__ u16 sh_h1[2][16 * 136];

  s16x8 B0ih[3];
  s16x8 B0hh[3][4];
  s16x8 B1ih[3][4];
  s16x8 B1hh[3][4];
  float bi0[3], bh0[3], bi1[3], bh1[3];
#pragma unroll
  for (int g = 0; g < 3; ++g) {
    int j = g * 128 + c;
    bi0[g] = bih0[j]; bh0[g] = bhh0[j];
    bi1[g] = bih1[j]; bh1[g] = bhh1[j];
    B0ih[g] = *(const s16x8*)(Wih0 + j * 32 + quad * 8);
#pragma unroll
    for (int kk = 0; kk < 4; ++kk) {
      B0hh[g][kk] = *(const s16x8*)(Whh0 + j * 128 + kk * 32 + quad * 8);
      B1ih[g][kk] = *(const s16x8*)(Wih1 + j * 128 + kk * 32 + quad * 8);
      B1hh[g][kk] = *(const s16x8*)(Whh1 + j * 128 + kk * 32 + quad * 8);
    }
  }
  float h0reg[4] = {0.f, 0.f, 0.f, 0.f};
  float h1reg[4] = {0.f, 0.f, 0.f, 0.f};
  for (int idx = tid; idx < 16 * 136; idx += 512) {
    sh_h0[0][idx] = 0; sh_h1[0][idx] = 0;
  }
  const int xr = tid >> 5, xc = tid & 31;
  float xpre = x[(size_t)(r0 + xr) * 2048 + xc];      // x(0)
  __syncthreads();

  const f32x4 zz4 = {0.f, 0.f, 0.f, 0.f};
  for (int t = 0; t < 64; ++t) {
    const int cur = t & 1, nxt = cur ^ 1;
    sh_x[xr * 40 + xc] = f2bf(xpre);
    __syncthreads();   // B1: x(t) staged; h0(t-1)/h1(t-1) visible
    s16x8 ax = *(const s16x8*)(sh_x + l16 * 40 + quad * 8);
    s16x8 ah0[4], ah1[4];
#pragma unroll
    for (int kk = 0; kk < 4; ++kk) {
      ah0[kk] = *(const s16x8*)(sh_h0[cur] + l16 * 136 + kk * 32 + quad * 8);
      ah1[kk] = *(const s16x8*)(sh_h1[cur] + l16 * 136 + kk * 32 + quad * 8);
    }
    if (t < 63) xpre = x[(size_t)(r0 + xr) * 2048 + (t + 1) * 32 + xc];

    // ---- layer 0
    {
      f32x4 ai[3], ah[3];
#pragma unroll
      for (int g = 0; g < 3; ++g) { ai[g] = mfma16(ax, B0ih[g], zz4); ah[g] = zz4; }
#pragma unroll
      for (int g = 0; g < 3; ++g)
#pragma unroll
        for (int kk = 0; kk < 4; ++kk) ah[g] = mfma16(ah0[kk], B0hh[g][kk], ah[g]);
#pragma unroll
      for (int i = 0; i < 4; ++i) {
        int m = quad * 4 + i;
        float rr = sigmf(ai[0][i] + bi0[0] + ah[0][i] + bh0[0]);
        float zg = sigmf(ai[1][i] + bi0[1] + ah[1][i] + bh0[1]);
        float nn = tanhf_fast(ai[2][i] + bi0[2] + rr * (ah[2][i] + bh0[2]));
        float hnew = (1.f - zg) * nn + zg * h0reg[i];
        h0reg[i] = hnew;
        sh_h0[nxt][m * 136 + c] = f2bf(hnew);
      }
    }
    __syncthreads();   // B2: h0(t) visible as layer-1 x input
    // ---- layer 1
    {
      s16x8 a1x[4];
#pragma unroll
      for (int kk = 0; kk < 4; ++kk)
        a1x[kk] = *(const s16x8*)(sh_h0[nxt] + l16 * 136 + kk * 32 + quad * 8);
      f32x4 ai[3], ah[3];
#pragma unroll
      for (int g = 0; g < 3; ++g) { ai[g] = zz4; ah[g] = zz4; }
#pragma unroll
      for (int g = 0; g < 3; ++g)
#pragma unroll
        for (int kk = 0; kk < 4; ++kk) {
          ai[g] = mfma16(a1x[kk], B1ih[g][kk], ai[g]);
          ah[g] = mfma16(ah1[kk], B1hh[g][kk], ah[g]);
        }
#pragma unroll
      for (int i = 0; i < 4; ++i) {
        int m = quad * 4 + i;
        float rr = sigmf(ai[0][i] + bi1[0] + ah[0][i] + bh1[0]);
        float zg = sigmf(ai[1][i] + bi1[1] + ah[1][i] + bh1[1]);
        float nn = tanhf_fast(ai[2][i] + bi1[2] + rr * (ah[2][i] + bh1[2]));
        float hnew = (1.f - zg) * nn + zg * h1reg[i];
        h1reg[i] = hnew;
        sh_h1[nxt][m * 136 + c] = f2bf(hnew);
        if (t == 63) g_out[(size_t)(r0 + m) * 128 + c] = hnew;
      }
    }
    // next B1 protects sh_h1[nxt]/sh_x rewrites
  }
}

// ---------------------------------------------------------------- row norms + bf16
__global__ void norm_cvt(const float* __restrict__ src, u16* __restrict__ dst,
                         float* __restrict__ rn)
{
  const int tid = threadIdx.x;
  const int wv = tid >> 6, l = tid & 63;
  const int row = blockIdx.x * 4 + wv;
  float2 f2 = *(const float2*)(src + (size_t)row * 128 + l * 2);
  float s = f2.x * f2.x + f2.y * f2.y;
#pragma unroll
  for (int off = 32; off >= 1; off >>= 1) s += __shfl_xor(s, off);
  ushort2 p; p.x = f2bf(f2.x); p.y = f2bf(f2.y);
  *(ushort2*)(dst + (size_t)row * 128 + l * 2) = p;
  if (l == 0) rn[row] = (s == 0.f) ? 0.f : rsqrtf(s);
}

// ---------------------------------------------------------------- cos-sim GEMM
template<int MODE>
__launch_bounds__(256, 1)
__global__ void cos_gemm(const u16* __restrict__ A, const u16* __restrict__ B,
                         const float* __restrict__ rnA, const float* __restrict__ rnB,
                         float* __restrict__ C, u16* __restrict__ E,
                         float* __restrict__ colsum)
{
  __shared__ u16 shA[128 * 136];
  __shared__ u16 shB[128 * 136];
  const int tid = threadIdx.x;
  const int l = tid & 63, wv = tid >> 6;
  const int quad = l >> 4, l16 = l & 15;
  const int i0 = blockIdx.y * 128, j0 = blockIdx.x * 128;
  {
    int r = tid >> 1, half = tid & 1;
    const int4* sa = (const int4*)(A + (size_t)(i0 + r) * 128 + half * 64);
    int4* da = (int4*)(shA + r * 136 + half * 64);
    const int4* sb = (const int4*)(B + (size_t)(j0 + r) * 128 + half * 64);
    int4* db = (int4*)(shB + r * 136 + half * 64);
#pragma unroll
    for (int q = 0; q < 8; ++q) { da[q] = sa[q]; db[q] = sb[q]; }
  }
  __syncthreads();
  const int wm = wv >> 1, wn = wv & 1;
  f32x4 acc[4][4];
  const f32x4 zz4 = {0.f, 0.f, 0.f, 0.f};
#pragma unroll
  for (int a = 0; a < 4; ++a)
#pragma unroll
    for (int b = 0; b < 4; ++b) acc[a][b] = zz4;
#pragma unroll
  for (int kk = 0; kk < 4; ++kk) {
    s16x8 af[4], bfr[4];
#pragma unroll
    for (int mt = 0; mt < 4; ++mt)
      af[mt] = *(const s16x8*)(shA + (wm * 64 + mt * 16 + l16) * 136 + kk * 32 + quad * 8);
#pragma unroll
    for (int nt = 0; nt < 4; ++nt)
      bfr[nt] = *(const s16x8*)(shB + (wn * 64 + nt * 16 + l16) * 136 + kk * 32 + quad * 8);
#pragma unroll
    for (int mt = 0; mt < 4; ++mt)
#pragma unroll
      for (int nt = 0; nt < 4; ++nt) acc[mt][nt] = mfma16(af[mt], bfr[nt], acc[mt][nt]);
  }
  float ra[4][4];
#pragma unroll
  for (int mt = 0; mt < 4; ++mt)
#pragma unroll
    for (int i = 0; i < 4; ++i) ra[mt][i] = rnA[i0 + wm * 64 + mt * 16 + quad * 4 + i];
#pragma unroll
  for (int nt = 0; nt < 4; ++nt) {
    int col = j0 + wn * 64 + nt * 16 + l16;
    float rb = rnB[col];
    float psum = 0.f;
#pragma unroll
    for (int mt = 0; mt < 4; ++mt)
#pragma unroll
      for (int i = 0; i < 4; ++i) {
        int row = i0 + wm * 64 + mt * 16 + quad * 4 + i;
        float v = acc[mt][nt][i] * ra[mt][i] * rb;
        if constexpr (MODE == 0) {
          C[(size_t)row * 4096 + col] = v;
        } else {
          float e = __expf(v);
          E[(size_t)row * 4096 + col] = f2bf(e);
          psum += e;
        }
      }
    if constexpr (MODE == 1) {
      psum += __shfl_xor(psum, 16);
      psum += __shfl_xor(psum, 32);
      if (quad == 0) atomicAdd(colsum + col, psum);
    }
  }
}

// ---------------------------------------------------------------- topK select (no scatter)
__launch_bounds__(256, 1)
__global__ void topk_select(const float* __restrict__ sim,
                            int* __restrict__ gselj, float* __restrict__ gselv,
                            int* __restrict__ cnt, int* __restrict__ touched)
{
  __shared__ unsigned hist[2048];
  __shared__ u64 cand[3072];
  __shared__ int selj[20];
  __shared__ unsigned ws4[4];
  __shared__ int shb, shcnt;
  const int tid = threadIdx.x;
  const int row = blockIdx.x;
  const int l = tid & 63, wv = tid >> 6;

  for (int i = tid; i < 2048; i += 256) hist[i] = 0;
  if (tid == 0) shcnt = 0;
  __syncthreads();

  unsigned key[4][4];
#pragma unroll
  for (int q = 0; q < 4; ++q) {
    int e0 = (q * 256 + tid) * 4;
    float4 v = *(const float4*)(sim + (size_t)row * 4096 + e0);
    key[q][0] = (e0 + 0 == row) ? 0u : (__float_as_uint(v.x) & 0x7FFFFFFFu);
    key[q][1] = (e0 + 1 == row) ? 0u : (__float_as_uint(v.y) & 0x7FFFFFFFu);
    key[q][2] = (e0 + 2 == row) ? 0u : (__float_as_uint(v.z) & 0x7FFFFFFFu);
    key[q][3] = (e0 + 3 == row) ? 0u : (__float_as_uint(v.w) & 0x7FFFFFFFu);
#pragma unroll
    for (int c = 0; c < 4; ++c) {
      unsigned bin = key[q][c] >> 19; if (bin > 2047u) bin = 2047u;
      atomicAdd(&hist[bin], 1u);
    }
  }
  __syncthreads();

  unsigned s = 0;
#pragma unroll
  for (int j = 0; j < 8; ++j) s += hist[tid * 8 + j];
  unsigned r = s;
#pragma unroll
  for (int off = 1; off < 64; off <<= 1) {
    unsigned o = __shfl_down(r, off);
    if (l + off < 64) r += o;
  }
  if (l == 0) ws4[wv] = r;
  __syncthreads();
  unsigned upper = 0;
  for (int q = wv + 1; q < 4; ++q) upper += ws4[q];
  unsigned excl = upper + (r - s);
  if (excl < 20u && excl + s >= 20u) {
    unsigned cum = excl;
    for (int j = 7; j >= 0; --j) {
      cum += hist[tid * 8 + j];
      if (cum >= 20u) { shb = tid * 8 + j; break; }
    }
  }
  __syncthreads();
  const unsigned b = (unsigned)shb;

#pragma unroll
  for (int q = 0; q < 4; ++q) {
    int e0 = (q * 256 + tid) * 4;
#pragma unroll
    for (int c = 0; c < 4; ++c) {
      unsigned bin = key[q][c] >> 19; if (bin > 2047u) bin = 2047u;
      if (bin >= b) {
        int p = atomicAdd(&shcnt, 1);
        if (p < 3072) cand[p] = ((u64)key[q][c] << 32) | (u64)(4095 - (e0 + c));
      }
    }
  }
  __syncthreads();
  const int C = (shcnt < 3072) ? shcnt : 3072;

  if (wv == 0) {
    for (int it = 0; it < 20; ++it) {
      u64 best = 0ull; int bpos = -1;
      for (int p = l; p < C; p += 64) {
        u64 cv = cand[p];
        if (cv > best) { best = cv; bpos = p; }
      }
      u64 mine = best;
#pragma unroll
      for (int off = 1; off < 64; off <<= 1) {
        u64 o = __shfl_xor(best, off);
        if (o > best) best = o;
      }
      if (mine == best && bpos >= 0 && best != 0ull) cand[bpos] = 0ull;
      if (l == 0) selj[it] = 4095 - (int)(best & 0xFFFull);
    }
  }
  __syncthreads();
  if (tid < 20) {
    int idx = selj[tid];
    float sv = (idx == row) ? 0.f : sim[(size_t)row * 4096 + idx];
    gselj[row * 20 + tid] = idx;
    gselv[row * 20 + tid] = sv;
    atomicAdd(&cnt[idx], 1);
    if (sv != 0.f) atomicOr(touched + idx, 1);
  }
}

// ---------------------------------------------------------------- exclusive scan of cnt[4096]
__launch_bounds__(1024, 1)
__global__ void scan4096(const int* __restrict__ cnt, int* __restrict__ offs,
                         int* __restrict__ cur)
{
  __shared__ int wsum[16];
  const int t = threadIdx.x, l = t & 63, wv = t >> 6;
  int4 c = ((const int4*)cnt)[t];
  int s = c.x + c.y + c.z + c.w;
  int ps = s;
#pragma unroll
  for (int off = 1; off < 64; off <<= 1) {
    int o = __shfl_up(ps, off);
    if (l >= off) ps += o;
  }
  if (l == 63) wsum[wv] = ps;
  __syncthreads();
  if (t == 0) {
    int a = 0;
#pragma unroll
    for (int q = 0; q < 16; ++q) { int x = wsum[q]; wsum[q] = a; a += x; }
  }
  __syncthreads();
  int base = wsum[wv] + (ps - s);
  int4 o4;
  o4.x = base; o4.y = o4.x + c.x; o4.z = o4.y + c.y; o4.w = o4.z + c.z;
  ((int4*)offs)[t] = o4;
  ((int4*)cur)[t] = o4;
}

// ---------------------------------------------------------------- CSR entry scatter
__global__ void scatter_entries(const int* __restrict__ gselj, const float* __restrict__ gselv,
                                int* __restrict__ cur, int* __restrict__ eid,
                                float* __restrict__ ev)
{
  unsigned idx = blockIdx.x * 256 + threadIdx.x;
  unsigned row = idx / 20u;
  int j = gselj[idx]; float v = gselv[idx];
  int pos = atomicAdd(&cur[j], 1);
  eid[pos] = (int)row; ev[pos] = v;
}

// ---------------------------------------------------------------- concept gather + cf fused
__launch_bounds__(128, 1)
__global__ void concept_cf(const int* __restrict__ offs, const int* __restrict__ cnt,
                           const int* __restrict__ eid, const float* __restrict__ ev,
                           const float* __restrict__ g, const float* __restrict__ sim,
                           const int* __restrict__ touched,
                           const float* __restrict__ Whc, const float* __restrict__ bhc,
                           float* __restrict__ cf, u16* __restrict__ cfbf,
                           float* __restrict__ rncf)
{
  __shared__ float shc[128];
  __shared__ float red2[2];
  const int j = blockIdx.x, d = threadIdx.x;
  const int l = d & 63, wv = d >> 6;
  const int off = offs[j], n = cnt[j];
  float acc = 0.f;
  for (int p = 0; p < n; ++p) {
    int i = eid[off + p]; float v = ev[off + p];
    acc += v * g[(size_t)i * 128 + d];
  }
  if (touched[j]) acc += sim[(size_t)j * 4097] * g[(size_t)j * 128 + d];
  float s = acc;
#pragma unroll
  for (int o = 32; o >= 1; o >>= 1) s += __shfl_xor(s, o);
  if (l == 0) red2[wv] = s;
  shc[d] = acc;
  __syncthreads();
  float valid = ((red2[0] + red2[1]) != 0.f) ? 1.f : 0.f;
  float o = bhc[d];
  const float4* wr = (const float4*)(Whc + (size_t)d * 128);
#pragma unroll 8
  for (int q = 0; q < 32; ++q) {
    float4 w4 = wr[q];
    float4 c4 = *((const float4*)shc + q);
    o += c4.x * w4.x + c4.y * w4.y + c4.z * w4.z + c4.w * w4.w;
  }
  float cfv = lrelu(o) * valid;
  cf[(size_t)j * 128 + d] = cfv;
  cfbf[(size_t)j * 128 + d] = f2bf(cfv);
  __syncthreads();
  float nn = cfv * cfv;
#pragma unroll
  for (int of = 32; of >= 1; of >>= 1) nn += __shfl_xor(nn, of);
  if (l == 0) red2[wv] = nn;
  __syncthreads();
  if (d == 0) {
    float q2 = red2[0] + red2[1];
    rncf[j] = (q2 == 0.f) ? 0.f : rsqrtf(q2);
  }
}

// ---------------------------------------------------------------- cfTs[n][c] = bf16(cf[c][n]/Z[c])
__global__ void scale_cfT(const float* __restrict__ cf, const float* __restrict__ colsum,
                          u16* __restrict__ cfTs)
{
  int idx = blockIdx.x * 256 + threadIdx.x;
  int n = idx >> 12, c = idx & 4095;
  float rz = __builtin_amdgcn_rcpf(colsum[c]);
  cfTs[idx] = f2bf(cf[(size_t)c * 128 + n] * rz);
}

// ---------------------------------------------------------------- hs_pre = E @ cfTs.T
__launch_bounds__(256, 1)
__global__ void attn_cf(const u16* __restrict__ attn, const u16* __restrict__ cfT,
                        float* __restrict__ hs_pre)
{
  __shared__ u16 shw[16 * 136];
  const int tid = threadIdx.x;
  const int l = tid & 63, wv = tid >> 6;
  const int quad = l >> 4, l16 = l & 15;
  const int r0 = blockIdx.x * 16;
  f32x4 acc[2];
  const f32x4 zz4 = {0.f, 0.f, 0.f, 0.f};
  acc[0] = zz4; acc[1] = zz4;
  for (int kc = 0; kc < 32; ++kc) {
    if (kc) __syncthreads();
    {
      int r = tid >> 4, seg = tid & 15;
      *(int4*)(shw + r * 136 + seg * 8) =
        *(const int4*)(attn + (size_t)(r0 + r) * 4096 + kc * 128 + seg * 8);
    }
    __syncthreads();
#pragma unroll
    for (int kk = 0; kk < 4; ++kk) {
      s16x8 a = *(const s16x8*)(shw + l16 * 136 + kk * 32 + quad * 8);
#pragma unroll
      for (int nt = 0; nt < 2; ++nt) {
        int n = wv * 32 + nt * 16 + l16;
        s16x8 b = *(const s16x8*)(cfT + (size_t)n * 4096 + kc * 128 + kk * 32 + quad * 8);
        acc[nt] = mfma16(a, b, acc[nt]);
      }
    }
  }
#pragma unroll
  for (int nt = 0; nt < 2; ++nt)
#pragma unroll
    for (int i = 0; i < 4; ++i) {
      int row = r0 + quad * 4 + i;
      int col = wv * 32 + nt * 16 + l16;
      hs_pre[(size_t)row * 128 + col] = acc[nt][i];
    }
}

// ---------------------------------------------------------------- head: MFMA chain
__launch_bounds__(256, 1)
__global__ void head_kernel(const float* __restrict__ hs_pre, const float* __restrict__ g,
                            const u16* __restrict__ whs, const u16* __restrict__ wfore,
                            const u16* __restrict__ wback, const u16* __restrict__ windi,
                            const float* __restrict__ b_hs, const float* __restrict__ b_fore,
                            const float* __restrict__ b_back, const float* __restrict__ b_indi,
                            const float* __restrict__ W_out, const float* __restrict__ b_out,
                            float* __restrict__ outp)
{
  __shared__ u16 bufin[16 * 136];
  __shared__ u16 bufB[16 * 136];
  __shared__ float bufF[16 * 132];
  __shared__ float shWout[128];
  const int tid = threadIdx.x;
  const int l = tid & 63, wv = tid >> 6;
  const int quad = l >> 4, l16 = l & 15;
  const int r0 = blockIdx.x * 16;
  const f32x4 zz4 = {0.f, 0.f, 0.f, 0.f};

  if (tid < 128) shWout[tid] = W_out[tid];
  for (int idx = tid; idx < 2048; idx += 256) {
    int j = idx >> 7, n = idx & 127;
    bufin[j * 136 + n] = f2bf(hs_pre[(size_t)(r0 + j) * 128 + n]);
  }
  __syncthreads();
  {
    s16x8 a[4];
#pragma unroll
    for (int kk = 0; kk < 4; ++kk)
      a[kk] = *(const s16x8*)(bufin + l16 * 136 + kk * 32 + quad * 8);
    f32x4 acc[2]; acc[0] = zz4; acc[1] = zz4;
#pragma unroll
    for (int nt = 0; nt < 2; ++nt) {
      int n = wv * 32 + nt * 16 + l16;
#pragma unroll
      for (int kk = 0; kk < 4; ++kk)
        acc[nt] = mfma16(a[kk], *(const s16x8*)(whs + n * 128 + kk * 32 + quad * 8), acc[nt]);
    }
#pragma unroll
    for (int nt = 0; nt < 2; ++nt) {
      int n = wv * 32 + nt * 16 + l16;
      float bb = b_hs[n];
#pragma unroll
      for (int i = 0; i < 4; ++i)
        bufB[(quad * 4 + i) * 136 + n] = f2bf(lrelu(acc[nt][i] + bb));
    }
  }
  __syncthreads();
  {
    s16x8 a[4];
#pragma unroll
    for (int kk = 0; kk < 4; ++kk)
      a[kk] = *(const s16x8*)(bufB + l16 * 136 + kk * 32 + quad * 8);
    f32x4 aF[2], aB[2]; aF[0] = zz4; aF[1] = zz4; aB[0] = zz4; aB[1] = zz4;
#pragma unroll
    for (int nt = 0; nt < 2; ++nt) {
      int n = wv * 32 + nt * 16 + l16;
#pragma unroll
      for (int kk = 0; kk < 4; ++kk) {
        aF[nt] = mfma16(a[kk], *(const s16x8*)(wfore + n * 128 + kk * 32 + quad * 8), aF[nt]);
        aB[nt] = mfma16(a[kk], *(const s16x8*)(wback + n * 128 + kk * 32 + quad * 8), aB[nt]);
      }
    }
#pragma unroll
    for (int nt = 0; nt < 2; ++nt) {
      int n = wv * 32 + nt * 16 + l16;
      float bf_ = b_fore[n], bb_ = b_back[n];
#pragma unroll
      for (int i = 0; i < 4; ++i) {
        int m = quad * 4 + i;
        bufF[m * 132 + n] = lrelu(aF[nt][i] + bf_);
        float back = lrelu(aB[nt][i] + bb_);
        float gv = g[(size_t)(r0 + m) * 128 + n];
        bufin[m * 136 + n] = f2bf(gv - back);
      }
    }
  }
  __syncthreads();
  {
    s16x8 a[4];
#pragma unroll
    for (int kk = 0; kk < 4; ++kk)
      a[kk] = *(const s16x8*)(bufin + l16 * 136 + kk * 32 + quad * 8);
    f32x4 acc[2]; acc[0] = zz4; acc[1] = zz4;
#pragma unroll
    for (int nt = 0; nt < 2; ++nt) {
      int n = wv * 32 + nt * 16 + l16;
#pragma unroll
      for (int kk = 0; kk < 4; ++kk)
        acc[nt] = mfma16(a[kk], *(const s16x8*)(windi + n * 128 + kk * 32 + quad * 8), acc[nt]);
    }
#pragma unroll
    for (int nt = 0; nt < 2; ++nt) {
      int n = wv * 32 + nt * 16 + l16;
      float bi_ = b_indi[n];
#pragma unroll
      for (int i = 0; i < 4; ++i)
        bufF[(quad * 4 + i) * 132 + n] += lrelu(acc[nt][i] + bi_);
    }
  }
  __syncthreads();
  if (tid < 16) {
    float s = b_out[0];
    const float* fr = bufF + tid * 132;
    for (int n = 0; n < 128; ++n) s += fr[n] * shWout[n];
    outp[r0 + tid] = s;
  }
}

// ---------------------------------------------------------------- workspace layout
static const size_t OFF_A       = 0;             // 67,108,864  sim fp32
static const size_t OFF_ATTN    = 67108864;      // 33,554,432  attn numerator bf16
static const size_t OFF_G       = 100663296;     //  2,097,152
static const size_t OFF_GBF     = 102760448;     //  1,048,576
static const size_t OFF_RNG     = 103809024;     //     16,384
static const size_t OFF_SELJ    = 103825408;     //    327,680
static const size_t OFF_SELV    = 104153088;     //    327,680
static const size_t OFF_EID     = 104480768;     //    327,680
static const size_t OFF_EV      = 104808448;     //    327,680
static const size_t OFF_CNT     = 105136128;     //     16,384  ┐
static const size_t OFF_TOUCH   = 105152512;     //     16,384  │ one 48KB memset
static const size_t OFF_COLSUM  = 105168896;     //     16,384  ┘
static const size_t OFF_OFFS    = 105185280;     //     16,384
static const size_t OFF_CUR     = 105201664;     //     16,384
static const size_t OFF_CF      = 105218048;     //  2,097,152
static const size_t OFF_CFBF    = 107315200;     //  1,048,576
static const size_t OFF_CFTS    = 108363776;     //  1,048,576
static const size_t OFF_RNCF    = 109412352;     //     16,384
static const size_t OFF_HSPRE   = 109428736;     //  2,097,152
static const size_t OFF_WB      = 111525888;     //    450,560  -> end 111,976,448

extern "C" void kernel_launch(void* const* d_in, const int* in_sizes, int n_in,
                              void* d_out, int out_size, void* d_ws, size_t ws_size,
                              hipStream_t stream)
{
  (void)in_sizes; (void)n_in; (void)out_size; (void)ws_size;
  const float* x      = (const float*)d_in[0];
  const float* Wih0   = (const float*)d_in[1];
  const float* Whh0   = (const float*)d_in[2];
  const float* bih0   = (const float*)d_in[3];
  const float* bhh0   = (const float*)d_in[4];
  const float* Wih1   = (const float*)d_in[5];
  const float* Whh1   = (const float*)d_in[6];
  const float* bih1   = (const float*)d_in[7];
  const float* bhh1   = (const float*)d_in[8];
  const float* W_hc   = (const float*)d_in[9];
  const float* b_hc   = (const float*)d_in[10];
  const float* W_hs   = (const float*)d_in[11];
  const float* b_hs   = (const float*)d_in[12];
  const float* W_fore = (const float*)d_in[13];
  const float* b_fore = (const float*)d_in[14];
  const float* W_back = (const float*)d_in[15];
  const float* b_back = (const float*)d_in[16];
  const float* W_indi = (const float*)d_in[17];
  const float* b_indi = (const float*)d_in[18];
  const float* W_out  = (const float*)d_in[19];
  const float* b_out  = (const float*)d_in[20];

  char* ws = (char*)d_ws;
  float* simbuf  = (float*)(ws + OFF_A);
  u16*   attnb   = (u16*)(ws + OFF_ATTN);
  float* gbuf    = (float*)(ws + OFF_G);
  u16*   gbf     = (u16*)(ws + OFF_GBF);
  float* rng     = (float*)(ws + OFF_RNG);
  int*   gselj   = (int*)(ws + OFF_SELJ);
  float* gselv   = (float*)(ws + OFF_SELV);
  int*   eid     = (int*)(ws + OFF_EID);
  float* ev      = (float*)(ws + OFF_EV);
  int*   cntb    = (int*)(ws + OFF_CNT);
  int*   touched = (int*)(ws + OFF_TOUCH);
  float* colsum  = (float*)(ws + OFF_COLSUM);
  int*   offsb   = (int*)(ws + OFF_OFFS);
  int*   curb    = (int*)(ws + OFF_CUR);
  float* cf      = (float*)(ws + OFF_CF);
  u16*   cfbf    = (u16*)(ws + OFF_CFBF);
  u16*   cfTs    = (u16*)(ws + OFF_CFTS);
  float* rncf    = (float*)(ws + OFF_RNCF);
  float* hs_pre  = (float*)(ws + OFF_HSPRE);
  u16*   wsB     = (u16*)(ws + OFF_WB);
  u16 *wih0b = wsB, *whh0b = wsB + 12288, *wih1b = wsB + 61440, *whh1b = wsB + 110592;
  u16 *whsb = wsB + 159744, *wforeb = wsB + 176128, *wbackb = wsB + 192512, *windib = wsB + 208896;

  cvt_all<<<880, 256, 0, stream>>>(Wih0, Whh0, Wih1, Whh1, W_hs, W_fore, W_back, W_indi, wsB);

  gru_fused<<<256, 512, 0, stream>>>(x, wih0b, whh0b, bih0, bhh0,
                                     wih1b, whh1b, bih1, bhh1, gbuf);

  norm_cvt<<<1024, 256, 0, stream>>>(gbuf, gbf, rng);
  cos_gemm<0><<<dim3(32, 32), 256, 0, stream>>>(gbf, gbf, rng, rng, simbuf,
                                                (u16*)nullptr, (float*)nullptr);

  hipMemsetAsync(ws + OFF_CNT, 0, 49152, stream);
  topk_select<<<4096, 256, 0, stream>>>(simbuf, gselj, gselv, cntb, touched);
  scan4096<<<1, 1024, 0, stream>>>(cntb, offsb, curb);
  scatter_entries<<<320, 256, 0, stream>>>(gselj, gselv, curb, eid, ev);
  concept_cf<<<4096, 128, 0, stream>>>(offsb, cntb, eid, ev, gbuf, simbuf, touched,
                                       W_hc, b_hc, cf, cfbf, rncf);

  cos_gemm<1><<<dim3(32, 32), 256, 0, stream>>>(gbf, cfbf, rng, rncf, (float*)nullptr,
                                                attnb, colsum);
  scale_cfT<<<2048, 256, 0, stream>>>(cf, colsum, cfTs);
  attn_cf<<<256, 256, 0, stream>>>(attnb, cfTs, hs_pre);

  head_kernel<<<256, 256, 0, stream>>>(hs_pre, gbuf, whsb, wforeb, wbackb, windib,
                                       b_hs, b_fore, b_back, b_indi, W_out, b_out,
                                       (float*)d_out);
}